// Round 2
// baseline (579.121 us; speedup 1.0000x reference)
//
#include <hip/hip_runtime.h>
#include <math.h>

#define B_   8
#define C_   512
#define L_   4096
#define H_   8
#define DK_  64
#define C2_  1024

typedef unsigned short ushort;
typedef short     bf16x8_t __attribute__((ext_vector_type(8)));
typedef float     f32x4_t  __attribute__((ext_vector_type(4)));
typedef unsigned short u16x8 __attribute__((ext_vector_type(8)));
typedef unsigned short u16x4 __attribute__((ext_vector_type(4)));

__device__ __forceinline__ float bf2f(ushort u) {
    unsigned int x = ((unsigned int)u) << 16;
    float f; __builtin_memcpy(&f, &x, 4); return f;
}
__device__ __forceinline__ ushort f2bf(float f) {
    unsigned int x; __builtin_memcpy(&x, &f, 4);
    x = (x + 0x7FFFu + ((x >> 16) & 1u)) >> 16;   // RNE
    return (ushort)x;
}

#define GLOAD_LDS16(gp, lp) \
    __builtin_amdgcn_global_load_lds((const __attribute__((address_space(1))) void*)(gp), \
                                     (__attribute__((address_space(3))) void*)(lp), 16, 0, 0)

// ---------------------------------------------------------------------------
// transpose_in: fp32 [B,C,L] -> bf16 [B*L, C].  grid (L/64, C/64, B), 256 thr
// ---------------------------------------------------------------------------
__global__ __launch_bounds__(256) void transpose_in(const float* __restrict__ in,
                                                    ushort* __restrict__ out)
{
    const int b = blockIdx.z, c0 = blockIdx.y * 64, l0 = blockIdx.x * 64;
    __shared__ float t[64][65];
    const int tid = threadIdx.x;
    {
        const int c = tid >> 4, l4 = (tid & 15) * 4;
        const float* ip = in + ((size_t)b * C_ + c0) * L_ + l0;
#pragma unroll
        for (int cc = c; cc < 64; cc += 16) {
            float4 v = *(const float4*)(ip + (size_t)cc * L_ + l4);
            t[l4 + 0][cc] = v.x; t[l4 + 1][cc] = v.y;
            t[l4 + 2][cc] = v.z; t[l4 + 3][cc] = v.w;
        }
    }
    __syncthreads();
    {
        const int l = tid >> 3, c8 = (tid & 7) * 8;
        ushort* op = out + ((size_t)b * L_ + l0) * C_ + c0;
#pragma unroll
        for (int ll = l; ll < 64; ll += 32) {
            u16x8 v;
#pragma unroll
            for (int i = 0; i < 8; ++i) v[i] = f2bf(t[ll][c8 + i]);
            *(u16x8*)(op + (size_t)ll * C_ + c8) = v;
        }
    }
}

// ---------------------------------------------------------------------------
// transpose_out: fp32 [B*L, C] -> fp32 [B,C,L].  grid (L/64, C/64, B)
// ---------------------------------------------------------------------------
__global__ __launch_bounds__(256) void transpose_out(const float* __restrict__ in,
                                                     float* __restrict__ out)
{
    const int b = blockIdx.z, c0 = blockIdx.y * 64, l0 = blockIdx.x * 64;
    __shared__ float t[64][65];   // t[c][l]
    const int tid = threadIdx.x;
    {
        const int l = tid >> 4, c4 = (tid & 15) * 4;
#pragma unroll
        for (int ll = l; ll < 64; ll += 16) {
            float4 v = *(const float4*)(in + ((size_t)(b * L_ + l0 + ll)) * C_ + c0 + c4);
            t[c4 + 0][ll] = v.x; t[c4 + 1][ll] = v.y;
            t[c4 + 2][ll] = v.z; t[c4 + 3][ll] = v.w;
        }
    }
    __syncthreads();
    {
        const int c = tid >> 4, l4 = (tid & 15) * 4;
        float* op = out + ((size_t)b * C_ + c0) * L_ + l0;
#pragma unroll
        for (int cc = c; cc < 64; cc += 16) {
            float4 v = {t[cc][l4], t[cc][l4 + 1], t[cc][l4 + 2], t[cc][l4 + 3]};
            *(float4*)(op + (size_t)cc * L_ + l4) = v;
        }
    }
}

__global__ __launch_bounds__(256) void cvt_bf16(const float* __restrict__ in,
                                                ushort* __restrict__ out, int n4)
{
    const int i = blockIdx.x * 256 + threadIdx.x;
    if (i < n4) {
        float4 v = *(const float4*)(in + 4 * (size_t)i);
        u16x4 o; o[0] = f2bf(v.x); o[1] = f2bf(v.y); o[2] = f2bf(v.z); o[3] = f2bf(v.w);
        *(u16x4*)(out + 4 * (size_t)i) = o;
    }
}

__global__ __launch_bounds__(256) void zero_kernel(float* __restrict__ p, int n4)
{
    const int i = blockIdx.x * 256 + threadIdx.x;
    if (i < n4) { float4 z = {0.f, 0.f, 0.f, 0.f}; *(float4*)(p + 4 * (size_t)i) = z; }
}

// ---------------------------------------------------------------------------
// conv_mfma: out[m,n] = act( sum_k A[m,k]*W[n,k] + bias[n] (+res[m,n]) )
// 128x128 tile, BK=32. 3-buffer counted-vmcnt pipeline (T3/T4 minimum form):
// tiles t and t+1 always in flight; s_waitcnt vmcnt(4) (never 0 in steady
// state) + raw s_barrier per K-step, tile t+2 issued after the barrier.
// MFMA operands SWAPPED (mfma(Wfrag, Afrag)) so each lane owns 4 consecutive
// output columns -> LDS-staged epilogue with coalesced 16B stores.
// ---------------------------------------------------------------------------
template<int ACT, bool HAS_RES>
__global__ __launch_bounds__(256) void conv_mfma(
    const ushort* __restrict__ A, const ushort* __restrict__ Wt,
    const float* __restrict__ bias, const ushort* __restrict__ res,
    ushort* __restrict__ out, int M, int N, int K)
{
    const int m0 = blockIdx.x * 128;
    const int n0 = blockIdx.y * 128;
    const int tid = threadIdx.x;
    const int w = tid >> 6, lane = tid & 63;
    const int wm = (w & 1) * 64, wn = (w >> 1) * 64;
    const int l16 = lane & 15, quad = lane >> 4;

    // 48 KB: 3 K-step buffers x (A 4096 | B 4096) ushorts.
    // Epilogue reuses the first 18432 ushorts as 4x [64][72] staging.
    __shared__ ushort smem[24576];

    f32x4_t acc[4][4];
#pragma unroll
    for (int i = 0; i < 4; ++i)
#pragma unroll
        for (int j = 0; j < 4; ++j) acc[i][j] = (f32x4_t){0.f, 0.f, 0.f, 0.f};

    const int srow = lane >> 2;       // 0..15
    const int sslot = lane & 3;       // physical 16B slot

    // staging addresses (k-slot swizzle folded into the global source)
    const ushort* gA[2]; const ushort* gB[2];
    int loff[2];
#pragma unroll
    for (int r = 0; r < 2; ++r) {
        const int row = r * 64 + w * 16 + srow;
        const int lk = sslot ^ ((row >> 2) & 3);
        gA[r] = A  + (size_t)(m0 + row) * K + lk * 8;
        gB[r] = Wt + (size_t)(n0 + row) * K + lk * 8;
        loff[r] = (r * 64 + w * 16) * 32;
    }

    const int nt = K >> 5;

    // prologue: tiles 0,1 into bufs 0,1 (8 outstanding loads per wave)
#pragma unroll
    for (int p = 0; p < 2; ++p) {
        ushort* lb = smem + p * 8192;
#pragma unroll
        for (int r = 0; r < 2; ++r) {
            GLOAD_LDS16(gA[r] + p * 32, lb + loff[r]);
            GLOAD_LDS16(gB[r] + p * 32, lb + 4096 + loff[r]);
        }
    }

    int buf = 0;                      // tile t lives in buf t%3
    for (int t = 0; t < nt; ++t) {
        // each wave issues exactly 4 loads/tile, in order -> vmcnt(4)
        // completes tile t while tile t+1's 4 loads stay in flight.
        if (t + 1 < nt) { asm volatile("s_waitcnt vmcnt(4)" ::: "memory"); }
        else            { asm volatile("s_waitcnt vmcnt(0)" ::: "memory"); }
        __builtin_amdgcn_s_barrier();
        __builtin_amdgcn_sched_barrier(0);   // pin ds_reads below the barrier
        if (t + 2 < nt) {
            // buf (t+2)%3 was last read at iter t-1; barrier above guards it
            const int nb2 = (buf >= 1) ? buf - 1 : buf + 2;   // (buf+2)%3
            ushort* lb = smem + nb2 * 8192;
            const size_t co = (size_t)(t + 2) * 32;
#pragma unroll
            for (int r = 0; r < 2; ++r) {
                GLOAD_LDS16(gA[r] + co, lb + loff[r]);
                GLOAD_LDS16(gB[r] + co, lb + 4096 + loff[r]);
            }
        }
        const ushort* bA = smem + buf * 8192;
        const ushort* bB = bA + 4096;
        bf16x8_t amf[4], wf[4];
#pragma unroll
        for (int i = 0; i < 4; ++i) {
            const int arow = wm + i * 16 + l16;
            amf[i] = *(const bf16x8_t*)(bA + arow * 32 + (quad ^ ((arow >> 2) & 3)) * 8);
            const int brow = wn + i * 16 + l16;
            wf[i]  = *(const bf16x8_t*)(bB + brow * 32 + (quad ^ ((brow >> 2) & 3)) * 8);
        }
        __builtin_amdgcn_s_setprio(1);
#pragma unroll
        for (int i = 0; i < 4; ++i)
#pragma unroll
            for (int j = 0; j < 4; ++j)
                acc[i][j] = __builtin_amdgcn_mfma_f32_16x16x32_bf16(wf[j], amf[i], acc[i][j], 0, 0, 0);
        __builtin_amdgcn_s_setprio(0);
        buf = (buf == 2) ? 0 : buf + 1;
    }

    // ---- epilogue ----
    // acc[i][j][r] = C[m0+wm+i*16+l16][n0+wn+j*16+quad*4+r]: 4 consecutive
    // columns per lane. bias/res/act, pack bf16x4, stage per-wave 64x64 tile
    // in LDS ([m][n], 72-ushort row stride), then coalesced u16x8 stores.
    __syncthreads();                    // all waves done with K-loop LDS
    ushort* sT = smem + w * 4608;       // 64 * 72 ushorts per wave
#pragma unroll
    for (int j = 0; j < 4; ++j) {
        const int nb = wn + j * 16 + quad * 4;     // block-local n base
        const float4 bo = *(const float4*)(bias + n0 + nb);
        const float bv[4] = {bo.x, bo.y, bo.z, bo.w};
#pragma unroll
        for (int i = 0; i < 4; ++i) {
            const int ml = i * 16 + l16;           // wave-local m row
            float v[4];
#pragma unroll
            for (int r = 0; r < 4; ++r) v[r] = acc[i][j][r] + bv[r];
            if (HAS_RES) {
                const u16x4 rv = *(const u16x4*)(res + (size_t)(m0 + wm + ml) * N + n0 + nb);
#pragma unroll
                for (int r = 0; r < 4; ++r) v[r] += bf2f(rv[r]);
            }
            if (ACT == 1) {
#pragma unroll
                for (int r = 0; r < 4; ++r) v[r] = (v[r] > 0.f) ? v[r] : (__expf(v[r]) - 1.f);
            }
            u16x4 pv;
#pragma unroll
            for (int r = 0; r < 4; ++r) pv[r] = f2bf(v[r]);
            *(u16x4*)(sT + ml * 72 + (nb - wn)) = pv;
        }
    }
    // same-wave readback (wave-private region, no barrier needed)
    {
        const int rr = lane >> 3, ch = lane & 7;
#pragma unroll
        for (int rep = 0; rep < 8; ++rep) {
            const int ml = rep * 8 + rr;
            const u16x8 vo = *(const u16x8*)(sT + ml * 72 + ch * 8);
            *(u16x8*)(out + (size_t)(m0 + wm + ml) * N + n0 + wn + ch * 8) = vo;
        }
    }
}

// ---------------------------------------------------------------------------
// kstat_chunk: per-chunk column (max, expsum) of k [B*L, C] bf16.
// grid (C/64, B*8), 256 thr. Chunk = 512 rows. stats[b*C+c][ch] float2.
// ---------------------------------------------------------------------------
__global__ __launch_bounds__(256) void kstat_chunk(const ushort* __restrict__ k,
                                                   float2* __restrict__ stats)
{
    const int cg = blockIdx.x;            // col group (64 cols)
    const int bc = blockIdx.y;            // b*8 + ch
    const int b = bc >> 3, ch = bc & 7;
    const int tid = threadIdx.x;
    const int g = tid & 7;                // 8-col subgroup
    const int kk = tid >> 3;              // 0..31 row worker
    const int w = tid >> 6, lane = tid & 63;
    const ushort* base = k + ((size_t)(b * L_) + ch * 512) * C_ + cg * 64 + g * 8;

    __shared__ float red[4][8][8];
    __shared__ float mcol[64];

    float fm[8];
#pragma unroll
    for (int i = 0; i < 8; ++i) fm[i] = -3.0e38f;
    for (int r = kk; r < 512; r += 32) {
        u16x8 v = *(const u16x8*)(base + (size_t)r * C_);
#pragma unroll
        for (int i = 0; i < 8; ++i) fm[i] = fmaxf(fm[i], bf2f(v[i]));
    }
#pragma unroll
    for (int off = 8; off <= 32; off <<= 1)
#pragma unroll
        for (int i = 0; i < 8; ++i) fm[i] = fmaxf(fm[i], __shfl_xor(fm[i], off));
    if ((lane >> 3) == 0)
#pragma unroll
        for (int i = 0; i < 8; ++i) red[w][g][i] = fm[i];
    __syncthreads();
    if (tid < 64) {
        const int g2 = tid >> 3, j = tid & 7;
        mcol[g2 * 8 + j] = fmaxf(fmaxf(red[0][g2][j], red[1][g2][j]),
                                 fmaxf(red[2][g2][j], red[3][g2][j]));
    }
    __syncthreads();
    float fmc[8];
#pragma unroll
    for (int i = 0; i < 8; ++i) fmc[i] = mcol[g * 8 + i];

    float fs[8] = {};
    for (int r = kk; r < 512; r += 32) {
        u16x8 v = *(const u16x8*)(base + (size_t)r * C_);
#pragma unroll
        for (int i = 0; i < 8; ++i) fs[i] += __expf(bf2f(v[i]) - fmc[i]);
    }
#pragma unroll
    for (int off = 8; off <= 32; off <<= 1)
#pragma unroll
        for (int i = 0; i < 8; ++i) fs[i] += __shfl_xor(fs[i], off);
    __syncthreads();
    if ((lane >> 3) == 0)
#pragma unroll
        for (int i = 0; i < 8; ++i) red[w][g][i] = fs[i];
    __syncthreads();
    if (tid < 64) {
        const int g2 = tid >> 3, j = tid & 7;
        const float s = red[0][g2][j] + red[1][g2][j] + red[2][g2][j] + red[3][g2][j];
        const int c = cg * 64 + g2 * 8 + j;
        stats[((size_t)(b * C_ + c)) * 8 + ch] = make_float2(mcol[g2 * 8 + j], s);
    }
}

// ---------------------------------------------------------------------------
// kstat_merge: global (m, 1/S) per (b,c) from 8 chunk stats.
// ---------------------------------------------------------------------------
__global__ __launch_bounds__(256) void kstat_merge(const float2* __restrict__ stats,
                                                   float2* __restrict__ minv)
{
    const int i = blockIdx.x * 256 + threadIdx.x;
    if (i >= B_ * C_) return;
    float2 st[8];
    float m = -3.0e38f;
#pragma unroll
    for (int ch = 0; ch < 8; ++ch) { st[ch] = stats[(size_t)i * 8 + ch]; m = fmaxf(m, st[ch].x); }
    float s = 0.f;
#pragma unroll
    for (int ch = 0; ch < 8; ++ch) s += st[ch].y * __expf(st[ch].x - m);
    minv[i] = make_float2(m, 1.f / s);
}

// ---------------------------------------------------------------------------
// ctx_accum: ctxT[bh][dv][dk] += sum_l v[b,l,h*64+dv] * softmax_k[b,l,h*64+dk]
// k is RAW logits; softmax applied on the fly via minv. fp32 atomics.
// 16-way L split (1024 blocks, 4 blocks/CU = 50% occupancy); LDS row stride
// 76 floats makes the [srow][c8] float4 write pattern bank-uniform.
// ---------------------------------------------------------------------------
__global__ __launch_bounds__(256) void ctx_accum(
    const ushort* __restrict__ kk, const ushort* __restrict__ vv,
    const float2* __restrict__ minv, float* __restrict__ ctx)
{
    const int bh = blockIdx.y, b = bh >> 3, h = bh & 7;
    const int l0 = blockIdx.x * 256;
    const int tid = threadIdx.x;
    __shared__ float sK[32][76];
    __shared__ float sV[32][76];
    const int srow = tid >> 3, c8 = (tid & 7) * 8;
    const int dv4 = (tid & 15) * 4, dk4 = (tid >> 4) * 4;

    float2 cst[8];
    {
        const float2* mp = minv + (size_t)b * C_ + h * 64 + c8;
#pragma unroll
        for (int i = 0; i < 8; ++i) cst[i] = mp[i];
    }
    float acc[4][4] = {};

    for (int lt = 0; lt < 256; lt += 32) {
        const size_t gbase = ((size_t)(b * L_ + l0 + lt + srow)) * C_ + h * 64 + c8;
        u16x8 kv = *(const u16x8*)(kk + gbase);
        u16x8 vvv = *(const u16x8*)(vv + gbase);
        __syncthreads();
        float fk[8], fv[8];
#pragma unroll
        for (int i = 0; i < 8; ++i) {
            fk[i] = __expf(bf2f(kv[i]) - cst[i].x) * cst[i].y;
            fv[i] = bf2f(vvv[i]);
        }
        *(float4*)&sK[srow][c8]     = (float4){fk[0], fk[1], fk[2], fk[3]};
        *(float4*)&sK[srow][c8 + 4] = (float4){fk[4], fk[5], fk[6], fk[7]};
        *(float4*)&sV[srow][c8]     = (float4){fv[0], fv[1], fv[2], fv[3]};
        *(float4*)&sV[srow][c8 + 4] = (float4){fv[4], fv[5], fv[6], fv[7]};
        __syncthreads();
#pragma unroll
        for (int ll = 0; ll < 32; ++ll) {
            const float4 a = *(const float4*)&sV[ll][dv4];
            const float4 bb = *(const float4*)&sK[ll][dk4];
            const float av[4] = {a.x, a.y, a.z, a.w};
            const float bv[4] = {bb.x, bb.y, bb.z, bb.w};
#pragma unroll
            for (int i = 0; i < 4; ++i)
#pragma unroll
                for (int j = 0; j < 4; ++j)
                    acc[i][j] = fmaf(av[i], bv[j], acc[i][j]);
        }
    }
    float* cp = ctx + (size_t)bh * 4096;
#pragma unroll
    for (int i = 0; i < 4; ++i)
#pragma unroll
        for (int j = 0; j < 4; ++j)
            atomicAdd(&cp[(dv4 + i) * 64 + (dk4 + j)], acc[i][j]);
}

// ---------------------------------------------------------------------------
// att_mfma: att[b,l,h*64+dv] = sum_dk softmax_q[...dk] * ctxT[bh][dv][dk]
// q is RAW logits; per-row softmax over 64 dk fused into the staging loop
// (8 lanes/row shuffle-reduce). grid (L/128, B*H), 256 thr.
// ---------------------------------------------------------------------------
__global__ __launch_bounds__(256) void att_mfma(
    const ushort* __restrict__ q, const float* __restrict__ ctx,
    ushort* __restrict__ att)
{
    const int bh = blockIdx.y, b = bh >> 3, h = bh & 7;
    const int l0 = blockIdx.x * 128;
    const int tid = threadIdx.x, w = tid >> 6, lane = tid & 63;
    const int l16 = lane & 15, quad = lane >> 4;

    __shared__ ushort sQ[128 * 72];   // [l][dk]
    __shared__ ushort sC[64 * 72];    // [dv][dk]

    {
        const int part = tid & 7;
#pragma unroll
        for (int rr = tid >> 3; rr < 128; rr += 32) {
            u16x8 v = *(const u16x8*)(q + ((size_t)(b * L_ + l0 + rr)) * C_ + h * 64 + part * 8);
            float f[8], m = -3.0e38f;
#pragma unroll
            for (int i = 0; i < 8; ++i) { f[i] = bf2f(v[i]); m = fmaxf(m, f[i]); }
            m = fmaxf(m, __shfl_xor(m, 1));
            m = fmaxf(m, __shfl_xor(m, 2));
            m = fmaxf(m, __shfl_xor(m, 4));
            float s = 0.f;
#pragma unroll
            for (int i = 0; i < 8; ++i) { f[i] = __expf(f[i] - m); s += f[i]; }
            s += __shfl_xor(s, 1); s += __shfl_xor(s, 2); s += __shfl_xor(s, 4);
            const float inv = 1.f / s;
            u16x8 o;
#pragma unroll
            for (int i = 0; i < 8; ++i) o[i] = f2bf(f[i] * inv);
            *(u16x8*)(sQ + rr * 72 + part * 8) = o;
        }
        const int dv = tid >> 2, dk0 = (tid & 3) * 16;
        const float* cp = ctx + (size_t)bh * 4096 + dv * 64 + dk0;
#pragma unroll
        for (int i = 0; i < 16; ++i) sC[dv * 72 + dk0 + i] = f2bf(cp[i]);
    }
    __syncthreads();

    f32x4_t acc[2][4];
#pragma unroll
    for (int i = 0; i < 2; ++i)
#pragma unroll
        for (int j = 0; j < 4; ++j) acc[i][j] = (f32x4_t){0.f, 0.f, 0.f, 0.f};

#pragma unroll
    for (int ks = 0; ks < 2; ++ks) {
        const int k0 = ks * 32;
        bf16x8_t aq[2], bc[4];
#pragma unroll
        for (int i = 0; i < 2; ++i)
            aq[i] = *(const bf16x8_t*)(sQ + (w * 32 + i * 16 + l16) * 72 + k0 + quad * 8);
#pragma unroll
        for (int j = 0; j < 4; ++j)
            bc[j] = *(const bf16x8_t*)(sC + (j * 16 + l16) * 72 + k0 + quad * 8);
#pragma unroll
        for (int i = 0; i < 2; ++i)
#pragma unroll
            for (int j = 0; j < 4; ++j)
                acc[i][j] = __builtin_amdgcn_mfma_f32_16x16x32_bf16(aq[i], bc[j], acc[i][j], 0, 0, 0);
    }

#pragma unroll
    for (int j = 0; j < 4; ++j)
#pragma unroll
        for (int i = 0; i < 2; ++i) {
            const int mb = l0 + w * 32 + i * 16 + quad * 4;
#pragma unroll
            for (int r = 0; r < 4; ++r)
                att[((size_t)(b * L_ + mb + r)) * C_ + h * 64 + j * 16 + l16] = f2bf(acc[i][j][r]);
        }
}

// ---------------------------------------------------------------------------
// LayerNorm over 512 contiguous channels; wave per row.
// ---------------------------------------------------------------------------
template<bool OUTF32>
__global__ __launch_bounds__(256) void ln_row(
    const ushort* __restrict__ in, const float* __restrict__ g,
    const float* __restrict__ be, ushort* __restrict__ outb,
    float* __restrict__ outf)
{
    const int tid = threadIdx.x, w = tid >> 6, lane = tid & 63;
    const size_t row = (size_t)blockIdx.x * 4 + w;
    const ushort* p = in + row * C_ + lane * 8;
    u16x8 v = *(const u16x8*)p;
    float f[8], s = 0.f, s2 = 0.f;
#pragma unroll
    for (int i = 0; i < 8; ++i) { f[i] = bf2f(v[i]); s += f[i]; s2 = fmaf(f[i], f[i], s2); }
#pragma unroll
    for (int o = 1; o < 64; o <<= 1) { s += __shfl_xor(s, o); s2 += __shfl_xor(s2, o); }
    const float mean = s * (1.f / C_);
    const float var  = s2 * (1.f / C_) - mean * mean;
    const float inv  = rsqrtf(var + 1e-5f);
    if (OUTF32) {
        float* op = outf + row * C_ + lane * 8;
#pragma unroll
        for (int i = 0; i < 8; ++i)
            op[i] = (f[i] - mean) * inv * g[lane * 8 + i] + be[lane * 8 + i];
    } else {
        u16x8 ov;
#pragma unroll
        for (int i = 0; i < 8; ++i)
            ov[i] = f2bf((f[i] - mean) * inv * g[lane * 8 + i] + be[lane * 8 + i]);
        *(u16x8*)(outb + row * C_ + lane * 8) = ov;
    }
}

// ---------------------------------------------------------------------------
extern "C" void kernel_launch(void* const* d_in, const int* in_sizes, int n_in,
                              void* d_out, int out_size, void* d_ws, size_t ws_size,
                              hipStream_t stream)
{
    const float* z1  = (const float*)d_in[0];
    const float* z2  = (const float*)d_in[1];
    const float* Wq  = (const float*)d_in[2];
    const float* bq  = (const float*)d_in[3];
    const float* Wk  = (const float*)d_in[4];
    const float* bk  = (const float*)d_in[5];
    const float* Wv  = (const float*)d_in[6];
    const float* bv  = (const float*)d_in[7];
    const float* Wr  = (const float*)d_in[8];
    const float* br  = (const float*)d_in[9];
    const float* g1  = (const float*)d_in[10];
    const float* be1 = (const float*)d_in[11];
    const float* W1  = (const float*)d_in[12];
    const float* b1  = (const float*)d_in[13];
    const float* W2  = (const float*)d_in[14];
    const float* b2  = (const float*)d_in[15];
    const float* g2  = (const float*)d_in[16];
    const float* be2 = (const float*)d_in[17];
    float* out = (float*)d_out;

    const size_t SB = (size_t)B_ * L_ * C_;     // 16.78M elems per bf16 buffer
    ushort* ws16 = (ushort*)d_ws;
    ushort* b0v = ws16;            // z1t -> y
    ushort* b1v = ws16 + SB;       // z2t -> att
    ushort* b2v = ws16 + 2 * SB;   // q(raw) -> z -> yf32(lo)
    ushort* b3v = ws16 + 3 * SB;   // k(raw) -> x -> yf32(hi)
    ushort* wb  = ws16 + 4 * SB;   // bf16 weights (4MB)
    ushort* wbq = wb;
    ushort* wbk = wb + 262144;
    ushort* wbv = wb + 524288;
    ushort* wbr = wb + 786432;
    ushort* wb1 = wb + 1048576;
    ushort* wb2 = wb + 1572864;
    float*  ctxf = (float*)(wb + 2097152);       // [B*H,64,64] fp32 (256KB)
    float2* stats = (float2*)(ctxf + 65536);     // [B*C][8] (256KB)
    float2* minv  = stats + (size_t)B_ * C_ * 8; // [B*C] (32KB)
    ushort* vbuf = (ushort*)d_out;               // v lives in d_out
    ushort* hbuf = (ushort*)d_out;               // h: [B*L, 1024] bf16
    float*  yf32 = (float*)b2v;                  // spans b2v+b3v

    const dim3 blk(256);
    const int M = B_ * L_;   // 32768

    // 0) input transposes + weight casts
    transpose_in<<<dim3(L_/64, C_/64, B_), blk, 0, stream>>>(z1, b0v);
    transpose_in<<<dim3(L_/64, C_/64, B_), blk, 0, stream>>>(z2, b1v);
    cvt_bf16<<<dim3(262144/4/256), blk, 0, stream>>>(Wq, wbq, 262144/4);
    cvt_bf16<<<dim3(262144/4/256), blk, 0, stream>>>(Wk, wbk, 262144/4);
    cvt_bf16<<<dim3(262144/4/256), blk, 0, stream>>>(Wv, wbv, 262144/4);
    cvt_bf16<<<dim3(262144/4/256), blk, 0, stream>>>(Wr, wbr, 262144/4);
    cvt_bf16<<<dim3(524288/4/256), blk, 0, stream>>>(W1, wb1, 524288/4);
    cvt_bf16<<<dim3(524288/4/256), blk, 0, stream>>>(W2, wb2, 524288/4);

    // 1) projections (MFMA); q and k stay RAW logits
    conv_mfma<0,false><<<dim3(M/128, C_/128), blk, 0, stream>>>(b0v, wbq, bq, nullptr, b2v, M, C_, C_);
    conv_mfma<0,false><<<dim3(M/128, C_/128), blk, 0, stream>>>(b1v, wbk, bk, nullptr, b3v, M, C_, C_);
    conv_mfma<0,false><<<dim3(M/128, C_/128), blk, 0, stream>>>(b1v, wbv, bv, nullptr, vbuf, M, C_, C_);

    // 2) k-softmax stats (parallel, chunked)
    kstat_chunk<<<dim3(C_/64, B_ * 8), blk, 0, stream>>>(b3v, stats);
    kstat_merge<<<dim3((B_ * C_ + 255) / 256), blk, 0, stream>>>(stats, minv);

    // 3) ctxT = V^T softmax(K)  (softmax fused, fp32 atomics over 16 l-splits)
    zero_kernel<<<dim3(65536/256), blk, 0, stream>>>(ctxf, 65536);
    ctx_accum<<<dim3(16, B_ * H_), blk, 0, stream>>>(b3v, vbuf, minv, ctxf);

    // 4) att = softmax(q) . ctxT^T per head (q-softmax fused); att -> b1v
    att_mfma<<<dim3(L_/128, B_ * H_), blk, 0, stream>>>(b2v, ctxf, b1v);

    // 5) z = Wr@att + br + z1t  -> b2v (q dead)
    conv_mfma<0,true><<<dim3(M/128, C_/128), blk, 0, stream>>>(b1v, wbr, br, b0v, b2v, M, C_, C_);

    // 6) x = LN1(z) -> b3v (k dead)
    ln_row<false><<<dim3(M/4), blk, 0, stream>>>(b2v, g1, be1, b3v, nullptr);

    // 7) h = ELU(W1@x) -> d_out (v dead)
    conv_mfma<1,false><<<dim3(M/128, C2_/128), blk, 0, stream>>>(b3v, wb1, b1, nullptr, hbuf, M, C2_, C_);

    // 8) y = W2@h -> b0v (z1t dead)
    conv_mfma<0,false><<<dim3(M/128, C_/128), blk, 0, stream>>>(hbuf, wb2, b2, nullptr, b0v, M, C_, C2_);

    // 9) LN2 -> fp32 [B*L,C] into b2v+b3v region (z,x dead)
    ln_row<true><<<dim3(M/4), blk, 0, stream>>>(b0v, g2, be2, nullptr, yf32);

    // 10) transpose to [B,C,L] fp32 -> d_out (h dead)
    transpose_out<<<dim3(L_/64, C_/64, B_), blk, 0, stream>>>(yf32, out);
}

// Round 3
// 553.480 us; speedup vs baseline: 1.0463x; 1.0463x over previous
//
#include <hip/hip_runtime.h>
#include <math.h>

#define B_   8
#define C_   512
#define L_   4096
#define H_   8
#define DK_  64
#define C2_  1024

typedef unsigned short ushort;
typedef short     bf16x8_t __attribute__((ext_vector_type(8)));
typedef float     f32x4_t  __attribute__((ext_vector_type(4)));
typedef unsigned short u16x8 __attribute__((ext_vector_type(8)));
typedef unsigned short u16x4 __attribute__((ext_vector_type(4)));

__device__ __forceinline__ float bf2f(ushort u) {
    unsigned int x = ((unsigned int)u) << 16;
    float f; __builtin_memcpy(&f, &x, 4); return f;
}
__device__ __forceinline__ ushort f2bf(float f) {
    unsigned int x; __builtin_memcpy(&x, &f, 4);
    x = (x + 0x7FFFu + ((x >> 16) & 1u)) >> 16;   // RNE
    return (ushort)x;
}

#define GLOAD_LDS16(gp, lp) \
    __builtin_amdgcn_global_load_lds((const __attribute__((address_space(1))) void*)(gp), \
                                     (__attribute__((address_space(3))) void*)(lp), 16, 0, 0)

// ---------------------------------------------------------------------------
// transpose_in: fp32 [B,C,L] -> bf16 [B*L, C].  grid (L/64, C/64, B), 256 thr
// ---------------------------------------------------------------------------
__global__ __launch_bounds__(256) void transpose_in(const float* __restrict__ in,
                                                    ushort* __restrict__ out)
{
    const int b = blockIdx.z, c0 = blockIdx.y * 64, l0 = blockIdx.x * 64;
    __shared__ float t[64][65];
    const int tid = threadIdx.x;
    {
        const int c = tid >> 4, l4 = (tid & 15) * 4;
        const float* ip = in + ((size_t)b * C_ + c0) * L_ + l0;
#pragma unroll
        for (int cc = c; cc < 64; cc += 16) {
            float4 v = *(const float4*)(ip + (size_t)cc * L_ + l4);
            t[l4 + 0][cc] = v.x; t[l4 + 1][cc] = v.y;
            t[l4 + 2][cc] = v.z; t[l4 + 3][cc] = v.w;
        }
    }
    __syncthreads();
    {
        const int l = tid >> 3, c8 = (tid & 7) * 8;
        ushort* op = out + ((size_t)b * L_ + l0) * C_ + c0;
#pragma unroll
        for (int ll = l; ll < 64; ll += 32) {
            u16x8 v;
#pragma unroll
            for (int i = 0; i < 8; ++i) v[i] = f2bf(t[ll][c8 + i]);
            *(u16x8*)(op + (size_t)ll * C_ + c8) = v;
        }
    }
}

// ---------------------------------------------------------------------------
// transpose_out: fp32 [B*L, C] -> fp32 [B,C,L].  grid (L/64, C/64, B)
// ---------------------------------------------------------------------------
__global__ __launch_bounds__(256) void transpose_out(const float* __restrict__ in,
                                                     float* __restrict__ out)
{
    const int b = blockIdx.z, c0 = blockIdx.y * 64, l0 = blockIdx.x * 64;
    __shared__ float t[64][65];   // t[c][l]
    const int tid = threadIdx.x;
    {
        const int l = tid >> 4, c4 = (tid & 15) * 4;
#pragma unroll
        for (int ll = l; ll < 64; ll += 16) {
            float4 v = *(const float4*)(in + ((size_t)(b * L_ + l0 + ll)) * C_ + c0 + c4);
            t[c4 + 0][ll] = v.x; t[c4 + 1][ll] = v.y;
            t[c4 + 2][ll] = v.z; t[c4 + 3][ll] = v.w;
        }
    }
    __syncthreads();
    {
        const int c = tid >> 4, l4 = (tid & 15) * 4;
        float* op = out + ((size_t)b * C_ + c0) * L_ + l0;
#pragma unroll
        for (int cc = c; cc < 64; cc += 16) {
            float4 v = {t[cc][l4], t[cc][l4 + 1], t[cc][l4 + 2], t[cc][l4 + 3]};
            *(float4*)(op + (size_t)cc * L_ + l4) = v;
        }
    }
}

__global__ __launch_bounds__(256) void cvt_bf16(const float* __restrict__ in,
                                                ushort* __restrict__ out, int n4)
{
    const int i = blockIdx.x * 256 + threadIdx.x;
    if (i < n4) {
        float4 v = *(const float4*)(in + 4 * (size_t)i);
        u16x4 o; o[0] = f2bf(v.x); o[1] = f2bf(v.y); o[2] = f2bf(v.z); o[3] = f2bf(v.w);
        *(u16x4*)(out + 4 * (size_t)i) = o;
    }
}

__global__ __launch_bounds__(256) void zero_kernel(float* __restrict__ p, int n4)
{
    const int i = blockIdx.x * 256 + threadIdx.x;
    if (i < n4) { float4 z = {0.f, 0.f, 0.f, 0.f}; *(float4*)(p + 4 * (size_t)i) = z; }
}

// ---------------------------------------------------------------------------
// conv_mfma: out[m,n] = act( sum_k A[m,k]*W[n,k] + bias[n] (+res[m,n]) )
// 256x256 tile, BK=32, 8 waves (2m x 4n, per-wave 128x64 out).
// 2-buffer pipeline, counted vmcnt(4): per K-step
//   B1 ; stage(t+1)->buf^1 ; s_waitcnt vmcnt(4) (own tile-t loads done,
//   t+1's stay in flight) ; B2 ; ds_read frags + 32 MFMA.
// 256 block-MFMA per barrier pair (4x the old 128^2 ratio).
// A/B staged with k-slot XOR swizzle folded into the global source
// (linear LDS dest as global_load_lds requires).
// Epilogue: mfma(wf, af) => lane holds 4 consecutive n for one m; direct
// u16x4 stores (32B/row segments; L2 merges to full lines).
// ---------------------------------------------------------------------------
template<int ACT, bool HAS_RES>
__global__ __launch_bounds__(512, 2) void conv_mfma(
    const ushort* __restrict__ A, const ushort* __restrict__ Wt,
    const float* __restrict__ bias, const ushort* __restrict__ res,
    ushort* __restrict__ out, int M, int N, int K)
{
    const int m0 = blockIdx.x * 256;
    const int n0 = blockIdx.y * 256;
    const int tid = threadIdx.x;
    const int w = tid >> 6, lane = tid & 63;
    const int wm = (w >> 2) * 128, wn = (w & 3) * 64;
    const int l16 = lane & 15, quad = lane >> 4;

    __shared__ ushort smem[32768];    // 64 KB: 2 bufs x (A 8192 | B 8192)

    // staging: thread covers row sRow (sweep 0) and 128+sRow (sweep 1),
    // 16B k-slot (tid&3), logical slot XOR-swizzled into the global source.
    const int sRow = tid >> 2;                       // 0..127
    const int sSwz = ((tid & 3) ^ (sRow & 3)) * 8;   // ushort offset
    const ushort* gA0 = A  + (size_t)(m0 + sRow) * K + sSwz;
    const ushort* gA1 = A  + (size_t)(m0 + 128 + sRow) * K + sSwz;
    const ushort* gB0 = Wt + (size_t)(n0 + sRow) * K + sSwz;
    const ushort* gB1 = Wt + (size_t)(n0 + 128 + sRow) * K + sSwz;
    const int dA0 = (w * 16) * 32;          // wave-uniform LDS dests (ushorts)
    const int dA1 = (128 + w * 16) * 32;

    f32x4_t acc[8][4];
#pragma unroll
    for (int i = 0; i < 8; ++i)
#pragma unroll
        for (int j = 0; j < 4; ++j) acc[i][j] = (f32x4_t){0.f, 0.f, 0.f, 0.f};

    const int nt = K >> 5;

    // prologue: tile 0 -> buf 0 (4 loads per thread outstanding)
    {
        ushort* bufA = smem;
        ushort* bufB = smem + 8192;
        GLOAD_LDS16(gA0, bufA + dA0);
        GLOAD_LDS16(gA1, bufA + dA1);
        GLOAD_LDS16(gB0, bufB + dA0);
        GLOAD_LDS16(gB1, bufB + dA1);
    }

    for (int t = 0; t < nt; ++t) {
        const ushort* bufA = smem + (t & 1) * 16384;
        const ushort* bufB = bufA + 8192;
        // B1: everyone finished reading buf^1 (read at t-1) -> safe to refill
        __builtin_amdgcn_s_barrier();
        asm volatile("" ::: "memory");
        if (t + 1 < nt) {
            ushort* nA = smem + ((t + 1) & 1) * 16384;
            ushort* nB = nA + 8192;
            const size_t co = (size_t)(t + 1) * 32;
            GLOAD_LDS16(gA0 + co, nA + dA0);
            GLOAD_LDS16(gA1 + co, nA + dA1);
            GLOAD_LDS16(gB0 + co, nB + dA0);
            GLOAD_LDS16(gB1 + co, nB + dA1);
            asm volatile("s_waitcnt vmcnt(4)" ::: "memory");  // tile t done
        } else {
            asm volatile("s_waitcnt vmcnt(0)" ::: "memory");
        }
        // B2: all waves' tile-t loads complete
        __builtin_amdgcn_s_barrier();
        asm volatile("" ::: "memory");

        bf16x8_t wf[4];
#pragma unroll
        for (int j = 0; j < 4; ++j) {
            const int br = wn + j * 16 + l16;
            wf[j] = *(const bf16x8_t*)(bufB + br * 32 + (quad ^ (br & 3)) * 8);
        }
        __builtin_amdgcn_s_setprio(1);
#pragma unroll
        for (int i = 0; i < 8; ++i) {
            const int ar = wm + i * 16 + l16;
            const bf16x8_t af = *(const bf16x8_t*)(bufA + ar * 32 + (quad ^ (ar & 3)) * 8);
#pragma unroll
            for (int j = 0; j < 4; ++j)
                acc[i][j] = __builtin_amdgcn_mfma_f32_16x16x32_bf16(wf[j], af, acc[i][j], 0, 0, 0);
        }
        __builtin_amdgcn_s_setprio(0);
    }

    // epilogue: acc[i][j][r] = C[m0+wm+i*16+l16][n0+wn+j*16+quad*4+r]
#pragma unroll
    for (int j = 0; j < 4; ++j) {
        const int nb = n0 + wn + j * 16 + quad * 4;
        const float4 bo = *(const float4*)(bias + nb);
        const float bv[4] = {bo.x, bo.y, bo.z, bo.w};
#pragma unroll
        for (int i = 0; i < 8; ++i) {
            const int m = m0 + wm + i * 16 + l16;
            float v[4];
#pragma unroll
            for (int r = 0; r < 4; ++r) v[r] = acc[i][j][r] + bv[r];
            if (HAS_RES) {
                const u16x4 rv = *(const u16x4*)(res + (size_t)m * N + nb);
#pragma unroll
                for (int r = 0; r < 4; ++r) v[r] += bf2f(rv[r]);
            }
            if (ACT == 1) {
#pragma unroll
                for (int r = 0; r < 4; ++r) v[r] = (v[r] > 0.f) ? v[r] : (__expf(v[r]) - 1.f);
            }
            u16x4 pv;
#pragma unroll
            for (int r = 0; r < 4; ++r) pv[r] = f2bf(v[r]);
            *(u16x4*)(out + (size_t)m * N + nb) = pv;
        }
    }
}

// ---------------------------------------------------------------------------
// kstat_chunk: per-chunk column (max, expsum) of k [B*L, C] bf16.
// grid (C/64, B*8), 256 thr. Chunk = 512 rows. stats[b*C+c][ch] float2.
// ---------------------------------------------------------------------------
__global__ __launch_bounds__(256) void kstat_chunk(const ushort* __restrict__ k,
                                                   float2* __restrict__ stats)
{
    const int cg = blockIdx.x;            // col group (64 cols)
    const int bc = blockIdx.y;            // b*8 + ch
    const int b = bc >> 3, ch = bc & 7;
    const int tid = threadIdx.x;
    const int g = tid & 7;                // 8-col subgroup
    const int kk = tid >> 3;              // 0..31 row worker
    const int w = tid >> 6, lane = tid & 63;
    const ushort* base = k + ((size_t)(b * L_) + ch * 512) * C_ + cg * 64 + g * 8;

    __shared__ float red[4][8][8];
    __shared__ float mcol[64];

    float fm[8];
#pragma unroll
    for (int i = 0; i < 8; ++i) fm[i] = -3.0e38f;
    for (int r = kk; r < 512; r += 32) {
        u16x8 v = *(const u16x8*)(base + (size_t)r * C_);
#pragma unroll
        for (int i = 0; i < 8; ++i) fm[i] = fmaxf(fm[i], bf2f(v[i]));
    }
#pragma unroll
    for (int off = 8; off <= 32; off <<= 1)
#pragma unroll
        for (int i = 0; i < 8; ++i) fm[i] = fmaxf(fm[i], __shfl_xor(fm[i], off));
    if ((lane >> 3) == 0)
#pragma unroll
        for (int i = 0; i < 8; ++i) red[w][g][i] = fm[i];
    __syncthreads();
    if (tid < 64) {
        const int g2 = tid >> 3, j = tid & 7;
        mcol[g2 * 8 + j] = fmaxf(fmaxf(red[0][g2][j], red[1][g2][j]),
                                 fmaxf(red[2][g2][j], red[3][g2][j]));
    }
    __syncthreads();
    float fmc[8];
#pragma unroll
    for (int i = 0; i < 8; ++i) fmc[i] = mcol[g * 8 + i];

    float fs[8] = {};
    for (int r = kk; r < 512; r += 32) {
        u16x8 v = *(const u16x8*)(base + (size_t)r * C_);
#pragma unroll
        for (int i = 0; i < 8; ++i) fs[i] += __expf(bf2f(v[i]) - fmc[i]);
    }
#pragma unroll
    for (int off = 8; off <= 32; off <<= 1)
#pragma unroll
        for (int i = 0; i < 8; ++i) fs[i] += __shfl_xor(fs[i], off);
    __syncthreads();
    if ((lane >> 3) == 0)
#pragma unroll
        for (int i = 0; i < 8; ++i) red[w][g][i] = fs[i];
    __syncthreads();
    if (tid < 64) {
        const int g2 = tid >> 3, j = tid & 7;
        const float s = red[0][g2][j] + red[1][g2][j] + red[2][g2][j] + red[3][g2][j];
        const int c = cg * 64 + g2 * 8 + j;
        stats[((size_t)(b * C_ + c)) * 8 + ch] = make_float2(mcol[g2 * 8 + j], s);
    }
}

// ---------------------------------------------------------------------------
// kstat_merge: global (m, 1/S) per (b,c) from 8 chunk stats.
// ---------------------------------------------------------------------------
__global__ __launch_bounds__(256) void kstat_merge(const float2* __restrict__ stats,
                                                   float2* __restrict__ minv)
{
    const int i = blockIdx.x * 256 + threadIdx.x;
    if (i >= B_ * C_) return;
    float2 st[8];
    float m = -3.0e38f;
#pragma unroll
    for (int ch = 0; ch < 8; ++ch) { st[ch] = stats[(size_t)i * 8 + ch]; m = fmaxf(m, st[ch].x); }
    float s = 0.f;
#pragma unroll
    for (int ch = 0; ch < 8; ++ch) s += st[ch].y * __expf(st[ch].x - m);
    minv[i] = make_float2(m, 1.f / s);
}

// ---------------------------------------------------------------------------
// ctx_mfma: ctxT[bh][dv][dk] += sum_l V[l][dv] * softmaxK[l][dk]  via MFMA.
// K (exp applied, bf16) and V staged TRANSPOSED [c][l] in LDS (stride 72);
// wave w computes dv rows [w*16, w*16+16) with mfma(vf, kf): D-row <-> first
// operand (harness-verified convention). grid (16, B*H), 256 thr.
// Threads 0..127 stage K (exp), 128..255 stage V (transpose passthrough).
// ---------------------------------------------------------------------------
__global__ __launch_bounds__(256) void ctx_mfma(
    const ushort* __restrict__ kk, const ushort* __restrict__ vv,
    const float2* __restrict__ minv, float* __restrict__ ctx)
{
    const int bh = blockIdx.y, b = bh >> 3, h = bh & 7;
    const int l0 = blockIdx.x * 256;
    const int tid = threadIdx.x, w = tid >> 6, lane = tid & 63;
    const int l16 = lane & 15, quad = lane >> 4;

    __shared__ ushort sK[64 * 72];   // [dk][l], stride 72 ushorts
    __shared__ ushort sV[64 * 72];   // [dv][l]

    const int grp = tid >> 7;        // 0 => K (exp), 1 => V
    const int st  = tid & 127;
    const int sc8 = (st & 7) * 8;    // c base 0..56
    const int sl4 = (st >> 3) * 4;   // l base 0..60
    const ushort* gsrc = (grp ? vv : kk)
        + ((size_t)(b * L_ + l0 + sl4)) * C_ + h * 64 + sc8;
    ushort* dst = grp ? sV : sK;

    float2 cst[8];
#pragma unroll
    for (int i = 0; i < 8; ++i)
        cst[i] = minv[(size_t)b * C_ + h * 64 + sc8 + i];

    f32x4_t acc[4];
#pragma unroll
    for (int j = 0; j < 4; ++j) acc[j] = (f32x4_t){0.f, 0.f, 0.f, 0.f};

    for (int tile = 0; tile < 4; ++tile) {
        u16x8 vr[4];
#pragma unroll
        for (int j = 0; j < 4; ++j)
            vr[j] = *(const u16x8*)(gsrc + ((size_t)(tile * 64 + j)) * C_);
        __syncthreads();              // prior tile's frag reads complete
        if (grp == 0) {
#pragma unroll
            for (int c = 0; c < 8; ++c) {
                u16x4 o;
#pragma unroll
                for (int j = 0; j < 4; ++j)
                    o[j] = f2bf(__expf(bf2f(vr[j][c]) - cst[c].x) * cst[c].y);
                *(u16x4*)(dst + (sc8 + c) * 72 + sl4) = o;
            }
        } else {
#pragma unroll
            for (int c = 0; c < 8; ++c) {
                u16x4 o;
#pragma unroll
                for (int j = 0; j < 4; ++j) o[j] = vr[j][c];
                *(u16x4*)(dst + (sc8 + c) * 72 + sl4) = o;
            }
        }
        __syncthreads();
#pragma unroll
        for (int k0 = 0; k0 < 64; k0 += 32) {
            const bf16x8_t vf = *(const bf16x8_t*)(sV + (w * 16 + l16) * 72 + k0 + quad * 8);
#pragma unroll
            for (int j = 0; j < 4; ++j) {
                const bf16x8_t kf = *(const bf16x8_t*)(sK + (j * 16 + l16) * 72 + k0 + quad * 8);
                acc[j] = __builtin_amdgcn_mfma_f32_16x16x32_bf16(vf, kf, acc[j], 0, 0, 0);
            }
        }
    }
    // acc[j][r]: dv = w*16 + quad*4 + r, dk = j*16 + l16
    float* cp = ctx + (size_t)bh * 4096;
#pragma unroll
    for (int j = 0; j < 4; ++j)
#pragma unroll
        for (int r = 0; r < 4; ++r)
            atomicAdd(&cp[(w * 16 + quad * 4 + r) * 64 + (j * 16 + l16)], acc[j][r]);
}

// ---------------------------------------------------------------------------
// att_mfma: att[b,l,h*64+dv] = sum_dk softmax_q[...dk] * ctxT[bh][dv][dk]
// q is RAW logits; per-row softmax over 64 dk fused into the staging loop
// (8 lanes/row shuffle-reduce). grid (L/128, B*H), 256 thr.
// ---------------------------------------------------------------------------
__global__ __launch_bounds__(256) void att_mfma(
    const ushort* __restrict__ q, const float* __restrict__ ctx,
    ushort* __restrict__ att)
{
    const int bh = blockIdx.y, b = bh >> 3, h = bh & 7;
    const int l0 = blockIdx.x * 128;
    const int tid = threadIdx.x, w = tid >> 6, lane = tid & 63;
    const int l16 = lane & 15, quad = lane >> 4;

    __shared__ ushort sQ[128 * 72];   // [l][dk]
    __shared__ ushort sC[64 * 72];    // [dv][dk]

    {
        const int part = tid & 7;
#pragma unroll
        for (int rr = tid >> 3; rr < 128; rr += 32) {
            u16x8 v = *(const u16x8*)(q + ((size_t)(b * L_ + l0 + rr)) * C_ + h * 64 + part * 8);
            float f[8], m = -3.0e38f;
#pragma unroll
            for (int i = 0; i < 8; ++i) { f[i] = bf2f(v[i]); m = fmaxf(m, f[i]); }
            m = fmaxf(m, __shfl_xor(m, 1));
            m = fmaxf(m, __shfl_xor(m, 2));
            m = fmaxf(m, __shfl_xor(m, 4));
            float s = 0.f;
#pragma unroll
            for (int i = 0; i < 8; ++i) { f[i] = __expf(f[i] - m); s += f[i]; }
            s += __shfl_xor(s, 1); s += __shfl_xor(s, 2); s += __shfl_xor(s, 4);
            const float inv = 1.f / s;
            u16x8 o;
#pragma unroll
            for (int i = 0; i < 8; ++i) o[i] = f2bf(f[i] * inv);
            *(u16x8*)(sQ + rr * 72 + part * 8) = o;
        }
        const int dv = tid >> 2, dk0 = (tid & 3) * 16;
        const float* cp = ctx + (size_t)bh * 4096 + dv * 64 + dk0;
#pragma unroll
        for (int i = 0; i < 16; ++i) sC[dv * 72 + dk0 + i] = f2bf(cp[i]);
    }
    __syncthreads();

    f32x4_t acc[2][4];
#pragma unroll
    for (int i = 0; i < 2; ++i)
#pragma unroll
        for (int j = 0; j < 4; ++j) acc[i][j] = (f32x4_t){0.f, 0.f, 0.f, 0.f};

#pragma unroll
    for (int ks = 0; ks < 2; ++ks) {
        const int k0 = ks * 32;
        bf16x8_t aq[2], bc[4];
#pragma unroll
        for (int i = 0; i < 2; ++i)
            aq[i] = *(const bf16x8_t*)(sQ + (w * 32 + i * 16 + l16) * 72 + k0 + quad * 8);
#pragma unroll
        for (int j = 0; j < 4; ++j)
            bc[j] = *(const bf16x8_t*)(sC + (j * 16 + l16) * 72 + k0 + quad * 8);
#pragma unroll
        for (int i = 0; i < 2; ++i)
#pragma unroll
            for (int j = 0; j < 4; ++j)
                acc[i][j] = __builtin_amdgcn_mfma_f32_16x16x32_bf16(aq[i], bc[j], acc[i][j], 0, 0, 0);
    }

#pragma unroll
    for (int j = 0; j < 4; ++j)
#pragma unroll
        for (int i = 0; i < 2; ++i) {
            const int mb = l0 + w * 32 + i * 16 + quad * 4;
#pragma unroll
            for (int r = 0; r < 4; ++r)
                att[((size_t)(b * L_ + mb + r)) * C_ + h * 64 + j * 16 + l16] = f2bf(acc[i][j][r]);
        }
}

// ---------------------------------------------------------------------------
// LayerNorm over 512 contiguous channels; wave per row.
// ---------------------------------------------------------------------------
template<bool OUTF32>
__global__ __launch_bounds__(256) void ln_row(
    const ushort* __restrict__ in, const float* __restrict__ g,
    const float* __restrict__ be, ushort* __restrict__ outb,
    float* __restrict__ outf)
{
    const int tid = threadIdx.x, w = tid >> 6, lane = tid & 63;
    const size_t row = (size_t)blockIdx.x * 4 + w;
    const ushort* p = in + row * C_ + lane * 8;
    u16x8 v = *(const u16x8*)p;
    float f[8], s = 0.f, s2 = 0.f;
#pragma unroll
    for (int i = 0; i < 8; ++i) { f[i] = bf2f(v[i]); s += f[i]; s2 = fmaf(f[i], f[i], s2); }
#pragma unroll
    for (int o = 1; o < 64; o <<= 1) { s += __shfl_xor(s, o); s2 += __shfl_xor(s2, o); }
    const float mean = s * (1.f / C_);
    const float var  = s2 * (1.f / C_) - mean * mean;
    const float inv  = rsqrtf(var + 1e-5f);
    if (OUTF32) {
        float* op = outf + row * C_ + lane * 8;
#pragma unroll
        for (int i = 0; i < 8; ++i)
            op[i] = (f[i] - mean) * inv * g[lane * 8 + i] + be[lane * 8 + i];
    } else {
        u16x8 ov;
#pragma unroll
        for (int i = 0; i < 8; ++i)
            ov[i] = f2bf((f[i] - mean) * inv * g[lane * 8 + i] + be[lane * 8 + i]);
        *(u16x8*)(outb + row * C_ + lane * 8) = ov;
    }
}

// ---------------------------------------------------------------------------
extern "C" void kernel_launch(void* const* d_in, const int* in_sizes, int n_in,
                              void* d_out, int out_size, void* d_ws, size_t ws_size,
                              hipStream_t stream)
{
    const float* z1  = (const float*)d_in[0];
    const float* z2  = (const float*)d_in[1];
    const float* Wq  = (const float*)d_in[2];
    const float* bq  = (const float*)d_in[3];
    const float* Wk  = (const float*)d_in[4];
    const float* bk  = (const float*)d_in[5];
    const float* Wv  = (const float*)d_in[6];
    const float* bv  = (const float*)d_in[7];
    const float* Wr  = (const float*)d_in[8];
    const float* br  = (const float*)d_in[9];
    const float* g1  = (const float*)d_in[10];
    const float* be1 = (const float*)d_in[11];
    const float* W1  = (const float*)d_in[12];
    const float* b1  = (const float*)d_in[13];
    const float* W2  = (const float*)d_in[14];
    const float* b2  = (const float*)d_in[15];
    const float* g2  = (const float*)d_in[16];
    const float* be2 = (const float*)d_in[17];
    float* out = (float*)d_out;

    const size_t SB = (size_t)B_ * L_ * C_;     // 16.78M elems per bf16 buffer
    ushort* ws16 = (ushort*)d_ws;
    ushort* b0v = ws16;            // z1t -> y
    ushort* b1v = ws16 + SB;       // z2t -> att
    ushort* b2v = ws16 + 2 * SB;   // q(raw) -> z -> yf32(lo)
    ushort* b3v = ws16 + 3 * SB;   // k(raw) -> x -> yf32(hi)
    ushort* wb  = ws16 + 4 * SB;   // bf16 weights (4MB)
    ushort* wbq = wb;
    ushort* wbk = wb + 262144;
    ushort* wbv = wb + 524288;
    ushort* wbr = wb + 786432;
    ushort* wb1 = wb + 1048576;
    ushort* wb2 = wb + 1572864;
    float*  ctxf = (float*)(wb + 2097152);       // [B*H,64,64] fp32 (256KB)
    float2* stats = (float2*)(ctxf + 65536);     // [B*C][8] (256KB)
    float2* minv  = stats + (size_t)B_ * C_ * 8; // [B*C] (32KB)
    ushort* vbuf = (ushort*)d_out;               // v lives in d_out
    ushort* hbuf = (ushort*)d_out;               // h: [B*L, 1024] bf16
    float*  yf32 = (float*)b2v;                  // spans b2v+b3v

    const dim3 blk(256);
    const dim3 blk512(512);
    const int M = B_ * L_;   // 32768

    // 0) input transposes + weight casts
    transpose_in<<<dim3(L_/64, C_/64, B_), blk, 0, stream>>>(z1, b0v);
    transpose_in<<<dim3(L_/64, C_/64, B_), blk, 0, stream>>>(z2, b1v);
    cvt_bf16<<<dim3(262144/4/256), blk, 0, stream>>>(Wq, wbq, 262144/4);
    cvt_bf16<<<dim3(262144/4/256), blk, 0, stream>>>(Wk, wbk, 262144/4);
    cvt_bf16<<<dim3(262144/4/256), blk, 0, stream>>>(Wv, wbv, 262144/4);
    cvt_bf16<<<dim3(262144/4/256), blk, 0, stream>>>(Wr, wbr, 262144/4);
    cvt_bf16<<<dim3(524288/4/256), blk, 0, stream>>>(W1, wb1, 524288/4);
    cvt_bf16<<<dim3(524288/4/256), blk, 0, stream>>>(W2, wb2, 524288/4);

    // 1) projections (MFMA); q and k stay RAW logits
    conv_mfma<0,false><<<dim3(M/256, C_/256), blk512, 0, stream>>>(b0v, wbq, bq, nullptr, b2v, M, C_, C_);
    conv_mfma<0,false><<<dim3(M/256, C_/256), blk512, 0, stream>>>(b1v, wbk, bk, nullptr, b3v, M, C_, C_);
    conv_mfma<0,false><<<dim3(M/256, C_/256), blk512, 0, stream>>>(b1v, wbv, bv, nullptr, vbuf, M, C_, C_);

    // 2) k-softmax stats (parallel, chunked)
    kstat_chunk<<<dim3(C_/64, B_ * 8), blk, 0, stream>>>(b3v, stats);
    kstat_merge<<<dim3((B_ * C_ + 255) / 256), blk, 0, stream>>>(stats, minv);

    // 3) ctxT = V^T softmax(K)  (softmax fused, MFMA, fp32 atomics, 16 l-splits)
    zero_kernel<<<dim3(65536/256), blk, 0, stream>>>(ctxf, 65536);
    ctx_mfma<<<dim3(16, B_ * H_), blk, 0, stream>>>(b3v, vbuf, minv, ctxf);

    // 4) att = softmax(q) . ctxT^T per head (q-softmax fused); att -> b1v
    att_mfma<<<dim3(L_/128, B_ * H_), blk, 0, stream>>>(b2v, ctxf, b1v);

    // 5) z = Wr@att + br + z1t  -> b2v (q dead)
    conv_mfma<0,true><<<dim3(M/256, C_/256), blk512, 0, stream>>>(b1v, wbr, br, b0v, b2v, M, C_, C_);

    // 6) x = LN1(z) -> b3v (k dead)
    ln_row<false><<<dim3(M/4), blk, 0, stream>>>(b2v, g1, be1, b3v, nullptr);

    // 7) h = ELU(W1@x) -> d_out (v dead)
    conv_mfma<1,false><<<dim3(M/256, C2_/256), blk512, 0, stream>>>(b3v, wb1, b1, nullptr, hbuf, M, C2_, C_);

    // 8) y = W2@h -> b0v (z1t dead)
    conv_mfma<0,false><<<dim3(M/256, C_/256), blk512, 0, stream>>>(hbuf, wb2, b2, nullptr, b0v, M, C_, C2_);

    // 9) LN2 -> fp32 [B*L,C] into b2v+b3v region (z,x dead)
    ln_row<true><<<dim3(M/4), blk, 0, stream>>>(b0v, g2, be2, nullptr, yf32);

    // 10) transpose to [B,C,L] fp32 -> d_out (h dead)
    transpose_out<<<dim3(L_/64, C_/64, B_), blk, 0, stream>>>(yf32, out);
}

// Round 4
// 519.496 us; speedup vs baseline: 1.1148x; 1.0654x over previous
//
#include <hip/hip_runtime.h>
#include <math.h>

#define B_   8
#define C_   512
#define L_   4096
#define H_   8
#define DK_  64
#define C2_  1024

typedef unsigned short ushort;
typedef short     bf16x8_t __attribute__((ext_vector_type(8)));
typedef float     f32x4_t  __attribute__((ext_vector_type(4)));
typedef unsigned short u16x8 __attribute__((ext_vector_type(8)));
typedef unsigned short u16x4 __attribute__((ext_vector_type(4)));

__device__ __forceinline__ float bf2f(ushort u) {
    unsigned int x = ((unsigned int)u) << 16;
    float f; __builtin_memcpy(&f, &x, 4); return f;
}
__device__ __forceinline__ ushort f2bf(float f) {
    unsigned int x; __builtin_memcpy(&x, &f, 4);
    x = (x + 0x7FFFu + ((x >> 16) & 1u)) >> 16;   // RNE
    return (ushort)x;
}

#define GLOAD_LDS16(gp, lp) \
    __builtin_amdgcn_global_load_lds((const __attribute__((address_space(1))) void*)(gp), \
                                     (__attribute__((address_space(3))) void*)(lp), 16, 0, 0)

// ---------------------------------------------------------------------------
// transpose_in: fp32 [B,C,L] -> bf16 [B*L, C].  grid (L/64, C/64, B), 256 thr
// ---------------------------------------------------------------------------
__global__ __launch_bounds__(256) void transpose_in(const float* __restrict__ in,
                                                    ushort* __restrict__ out)
{
    const int b = blockIdx.z, c0 = blockIdx.y * 64, l0 = blockIdx.x * 64;
    __shared__ float t[64][65];
    const int tid = threadIdx.x;
    {
        const int c = tid >> 4, l4 = (tid & 15) * 4;
        const float* ip = in + ((size_t)b * C_ + c0) * L_ + l0;
#pragma unroll
        for (int cc = c; cc < 64; cc += 16) {
            float4 v = *(const float4*)(ip + (size_t)cc * L_ + l4);
            t[l4 + 0][cc] = v.x; t[l4 + 1][cc] = v.y;
            t[l4 + 2][cc] = v.z; t[l4 + 3][cc] = v.w;
        }
    }
    __syncthreads();
    {
        const int l = tid >> 3, c8 = (tid & 7) * 8;
        ushort* op = out + ((size_t)b * L_ + l0) * C_ + c0;
#pragma unroll
        for (int ll = l; ll < 64; ll += 32) {
            u16x8 v;
#pragma unroll
            for (int i = 0; i < 8; ++i) v[i] = f2bf(t[ll][c8 + i]);
            *(u16x8*)(op + (size_t)ll * C_ + c8) = v;
        }
    }
}

// ---------------------------------------------------------------------------
// transpose_out: fp32 [B*L, C] -> fp32 [B,C,L].  grid (L/64, C/64, B)
// ---------------------------------------------------------------------------
__global__ __launch_bounds__(256) void transpose_out(const float* __restrict__ in,
                                                     float* __restrict__ out)
{
    const int b = blockIdx.z, c0 = blockIdx.y * 64, l0 = blockIdx.x * 64;
    __shared__ float t[64][65];   // t[c][l]
    const int tid = threadIdx.x;
    {
        const int l = tid >> 4, c4 = (tid & 15) * 4;
#pragma unroll
        for (int ll = l; ll < 64; ll += 16) {
            float4 v = *(const float4*)(in + ((size_t)(b * L_ + l0 + ll)) * C_ + c0 + c4);
            t[c4 + 0][ll] = v.x; t[c4 + 1][ll] = v.y;
            t[c4 + 2][ll] = v.z; t[c4 + 3][ll] = v.w;
        }
    }
    __syncthreads();
    {
        const int c = tid >> 4, l4 = (tid & 15) * 4;
        float* op = out + ((size_t)b * C_ + c0) * L_ + l0;
#pragma unroll
        for (int cc = c; cc < 64; cc += 16) {
            float4 v = {t[cc][l4], t[cc][l4 + 1], t[cc][l4 + 2], t[cc][l4 + 3]};
            *(float4*)(op + (size_t)cc * L_ + l4) = v;
        }
    }
}

__global__ __launch_bounds__(256) void cvt_bf16(const float* __restrict__ in,
                                                ushort* __restrict__ out, int n4)
{
    const int i = blockIdx.x * 256 + threadIdx.x;
    if (i < n4) {
        float4 v = *(const float4*)(in + 4 * (size_t)i);
        u16x4 o; o[0] = f2bf(v.x); o[1] = f2bf(v.y); o[2] = f2bf(v.z); o[3] = f2bf(v.w);
        *(u16x4*)(out + 4 * (size_t)i) = o;
    }
}

__global__ __launch_bounds__(256) void zero_kernel(float* __restrict__ p, int n4)
{
    const int i = blockIdx.x * 256 + threadIdx.x;
    if (i < n4) { float4 z = {0.f, 0.f, 0.f, 0.f}; *(float4*)(p + 4 * (size_t)i) = z; }
}

// ---------------------------------------------------------------------------
// conv_mfma: out[m,n] = act( sum_k A[m,k]*W[n,k] + bias[n] (+res[m,n]) )
// 256x256 tile, BK=64, 8 waves (2m x 4n), 4-phase schedule with counted
// vmcnt(6):
//   K-tile split into 4 k-quarters (16 k each, 8 KB A + 8 KB B).
//   Phase p of tile t: {issue stage of quarter p of tile t+1 (2 gloads),
//   s_waitcnt vmcnt(6) [leaves newest 3 quarter-stages in flight ->
//   guarantees the quarters phase p consumes are resident], s_barrier,
//   8 ds_read_b128 frags, 16 MFMA under setprio(1)}.
//   Loads never drain to 0; each load has 4 phases of lead time.
//   WAR on the next buffer is race-free by quarter-disjointness.
// LDS 128 KB: 2 bufs x (A[4 quarters][4096 ush] | B[4][4096]).
// Slot XOR-swizzle ((row>>2)&1 into the 8-halfword bit) folded identically
// into the pre-swizzled global source and the frag-read address.
// Epilogue: mfma(wf, af) => lane owns 4 consecutive n; LDS-staged per-wave
// 64x72 tiles -> coalesced u16x8 stores (verified R1 pattern).
// ---------------------------------------------------------------------------
template<int ACT, bool HAS_RES>
__global__ __launch_bounds__(512, 2) void conv_mfma(
    const ushort* __restrict__ A, const ushort* __restrict__ Wt,
    const float* __restrict__ bias, const ushort* __restrict__ res,
    ushort* __restrict__ out, int M, int N, int K)
{
    const int m0 = blockIdx.x * 256;
    const int n0 = blockIdx.y * 256;
    const int tid = threadIdx.x;
    const int w = tid >> 6, lane = tid & 63;
    const int wm2 = (w >> 2) * 128, wn = (w & 3) * 64;
    const int l16 = lane & 15, quad = lane >> 4;

    __shared__ ushort smem[65536];   // 128 KB

    // ---- staging (thread -> row sRow, 8-halfword slot sHalf) ----
    const int sRow = tid >> 1, sHalf = tid & 1;
    const int sh = sHalf ^ ((sRow >> 2) & 1);            // pre-swizzled source slot
    const ushort* gA = A  + (size_t)(m0 + sRow) * K + sh * 8;
    const ushort* gB = Wt + (size_t)(n0 + sRow) * K + sh * 8;
    // LDS dest: linear, waveBase + lane*16B as global_load_lds requires
    const int ldst = tid * 8;                            // ushort offset

    // ---- frag-read invariants ----
    const int baseA = wm2 + l16;
    const int baseB = wn + l16;
    const int hA = (quad & 1) ^ ((baseA >> 2) & 1);
    const int hB = (quad & 1) ^ ((baseB >> 2) & 1);
    const int qhi = (quad >> 1) * 4096;
    const int aoff = qhi + baseA * 16 + hA * 8;          // within buf
    const int boff = qhi + 16384 + baseB * 16 + hB * 8;

    f32x4_t acc[8][4];
#pragma unroll
    for (int i = 0; i < 8; ++i)
#pragma unroll
        for (int j = 0; j < 4; ++j) acc[i][j] = (f32x4_t){0.f, 0.f, 0.f, 0.f};

    const int nt = K >> 6;   // BK=64 tiles (K=512 -> 8, K=1024 -> 16)

    // prologue: all 4 quarters of tile 0 -> buf 0 (8 loads/thread in flight)
#pragma unroll
    for (int q = 0; q < 4; ++q) {
        GLOAD_LDS16(gA + q * 16, smem + q * 4096 + ldst);
        GLOAD_LDS16(gB + q * 16, smem + 16384 + q * 4096 + ldst);
    }

    for (int t = 0; t < nt; ++t) {
        const int cb = (t & 1) * 32768;
        const int nb = 32768 - cb;
        const bool pf = (t + 1 < nt);
#pragma unroll
        for (int p = 0; p < 4; ++p) {
            if (pf) {
                const int ko = (t + 1) * 64 + p * 16;
                GLOAD_LDS16(gA + ko, smem + nb + p * 4096 + ldst);
                GLOAD_LDS16(gB + ko, smem + nb + 16384 + p * 4096 + ldst);
                asm volatile("s_waitcnt vmcnt(6)" ::: "memory");
            } else {
                if (p < 2) { asm volatile("s_waitcnt vmcnt(4)" ::: "memory"); }
                else       { asm volatile("s_waitcnt vmcnt(0)" ::: "memory"); }
            }
            __builtin_amdgcn_s_barrier();
            asm volatile("" ::: "memory");

            const int ih = p & 1;
            const ushort* base = smem + cb + (p >> 1) * 8192;
            bf16x8_t wf[4], af[4];
#pragma unroll
            for (int x = 0; x < 4; ++x) {
                wf[x] = *(const bf16x8_t*)(base + boff + x * 256);
                af[x] = *(const bf16x8_t*)(base + aoff + (ih * 4 + x) * 256);
            }
            __builtin_amdgcn_s_setprio(1);
#pragma unroll
            for (int x = 0; x < 4; ++x)
#pragma unroll
                for (int j = 0; j < 4; ++j)
                    acc[ih * 4 + x][j] =
                        __builtin_amdgcn_mfma_f32_16x16x32_bf16(wf[j], af[x], acc[ih * 4 + x][j], 0, 0, 0);
            __builtin_amdgcn_s_setprio(0);
        }
    }

    // ---- epilogue: LDS-staged coalesced stores, two 64-row halves ----
    __syncthreads();                     // all frag reads done; smem reusable
    ushort* sT = smem + w * 4608;        // 64*72 ushorts per wave
#pragma unroll
    for (int h2 = 0; h2 < 2; ++h2) {
#pragma unroll
        for (int j = 0; j < 4; ++j) {
            const int nb4 = wn + j * 16 + quad * 4;          // block-local n
            const float4 bo = *(const float4*)(bias + n0 + nb4);
            const float bv[4] = {bo.x, bo.y, bo.z, bo.w};
#pragma unroll
            for (int x = 0; x < 4; ++x) {
                const int ml = x * 16 + l16;                 // row within half
                const int m = m0 + wm2 + h2 * 64 + ml;
                float v[4];
#pragma unroll
                for (int r = 0; r < 4; ++r) v[r] = acc[h2 * 4 + x][j][r] + bv[r];
                if (HAS_RES) {
                    const u16x4 rv = *(const u16x4*)(res + (size_t)m * N + n0 + nb4);
#pragma unroll
                    for (int r = 0; r < 4; ++r) v[r] += bf2f(rv[r]);
                }
                if (ACT == 1) {
#pragma unroll
                    for (int r = 0; r < 4; ++r) v[r] = (v[r] > 0.f) ? v[r] : (__expf(v[r]) - 1.f);
                }
                u16x4 pv;
#pragma unroll
                for (int r = 0; r < 4; ++r) pv[r] = f2bf(v[r]);
                *(u16x4*)(sT + ml * 72 + (nb4 - wn)) = pv;
            }
        }
        // same-wave readback (wave-private region)
        {
            const int rr = lane >> 3, ch = lane & 7;
#pragma unroll
            for (int rep = 0; rep < 8; ++rep) {
                const int ml = rep * 8 + rr;
                const u16x8 vo = *(const u16x8*)(sT + ml * 72 + ch * 8);
                *(u16x8*)(out + (size_t)(m0 + wm2 + h2 * 64 + ml) * N + n0 + wn + ch * 8) = vo;
            }
        }
    }
}

// ---------------------------------------------------------------------------
// kstat_chunk: per-chunk column (max, expsum) of k [B*L, C] bf16.
// grid (C/64, B*8), 256 thr. Chunk = 512 rows. stats[b*C+c][ch] float2.
// ---------------------------------------------------------------------------
__global__ __launch_bounds__(256) void kstat_chunk(const ushort* __restrict__ k,
                                                   float2* __restrict__ stats)
{
    const int cg = blockIdx.x;            // col group (64 cols)
    const int bc = blockIdx.y;            // b*8 + ch
    const int b = bc >> 3, ch = bc & 7;
    const int tid = threadIdx.x;
    const int g = tid & 7;                // 8-col subgroup
    const int kk = tid >> 3;              // 0..31 row worker
    const int w = tid >> 6, lane = tid & 63;
    const ushort* base = k + ((size_t)(b * L_) + ch * 512) * C_ + cg * 64 + g * 8;

    __shared__ float red[4][8][8];
    __shared__ float mcol[64];

    float fm[8];
#pragma unroll
    for (int i = 0; i < 8; ++i) fm[i] = -3.0e38f;
    for (int r = kk; r < 512; r += 32) {
        u16x8 v = *(const u16x8*)(base + (size_t)r * C_);
#pragma unroll
        for (int i = 0; i < 8; ++i) fm[i] = fmaxf(fm[i], bf2f(v[i]));
    }
#pragma unroll
    for (int off = 8; off <= 32; off <<= 1)
#pragma unroll
        for (int i = 0; i < 8; ++i) fm[i] = fmaxf(fm[i], __shfl_xor(fm[i], off));
    if ((lane >> 3) == 0)
#pragma unroll
        for (int i = 0; i < 8; ++i) red[w][g][i] = fm[i];
    __syncthreads();
    if (tid < 64) {
        const int g2 = tid >> 3, j = tid & 7;
        mcol[g2 * 8 + j] = fmaxf(fmaxf(red[0][g2][j], red[1][g2][j]),
                                 fmaxf(red[2][g2][j], red[3][g2][j]));
    }
    __syncthreads();
    float fmc[8];
#pragma unroll
    for (int i = 0; i < 8; ++i) fmc[i] = mcol[g * 8 + i];

    float fs[8] = {};
    for (int r = kk; r < 512; r += 32) {
        u16x8 v = *(const u16x8*)(base + (size_t)r * C_);
#pragma unroll
        for (int i = 0; i < 8; ++i) fs[i] += __expf(bf2f(v[i]) - fmc[i]);
    }
#pragma unroll
    for (int off = 8; off <= 32; off <<= 1)
#pragma unroll
        for (int i = 0; i < 8; ++i) fs[i] += __shfl_xor(fs[i], off);
    __syncthreads();
    if ((lane >> 3) == 0)
#pragma unroll
        for (int i = 0; i < 8; ++i) red[w][g][i] = fs[i];
    __syncthreads();
    if (tid < 64) {
        const int g2 = tid >> 3, j = tid & 7;
        const float s = red[0][g2][j] + red[1][g2][j] + red[2][g2][j] + red[3][g2][j];
        const int c = cg * 64 + g2 * 8 + j;
        stats[((size_t)(b * C_ + c)) * 8 + ch] = make_float2(mcol[g2 * 8 + j], s);
    }
}

// ---------------------------------------------------------------------------
// kstat_merge: global (m, 1/S) per (b,c) from 8 chunk stats.
// ---------------------------------------------------------------------------
__global__ __launch_bounds__(256) void kstat_merge(const float2* __restrict__ stats,
                                                   float2* __restrict__ minv)
{
    const int i = blockIdx.x * 256 + threadIdx.x;
    if (i >= B_ * C_) return;
    float2 st[8];
    float m = -3.0e38f;
#pragma unroll
    for (int ch = 0; ch < 8; ++ch) { st[ch] = stats[(size_t)i * 8 + ch]; m = fmaxf(m, st[ch].x); }
    float s = 0.f;
#pragma unroll
    for (int ch = 0; ch < 8; ++ch) s += st[ch].y * __expf(st[ch].x - m);
    minv[i] = make_float2(m, 1.f / s);
}

// ---------------------------------------------------------------------------
// ctx_mfma: ctxT[bh][dv][dk] += sum_l V[l][dv] * softmaxK[l][dk]  via MFMA.
// K (exp applied, bf16) and V staged TRANSPOSED [c][l] in LDS (stride 72);
// wave w computes dv rows [w*16, w*16+16) with mfma(vf, kf): D-row <-> first
// operand (harness-verified convention). grid (16, B*H), 256 thr.
// Threads 0..127 stage K (exp), 128..255 stage V (transpose passthrough).
// ---------------------------------------------------------------------------
__global__ __launch_bounds__(256) void ctx_mfma(
    const ushort* __restrict__ kk, const ushort* __restrict__ vv,
    const float2* __restrict__ minv, float* __restrict__ ctx)
{
    const int bh = blockIdx.y, b = bh >> 3, h = bh & 7;
    const int l0 = blockIdx.x * 256;
    const int tid = threadIdx.x, w = tid >> 6, lane = tid & 63;
    const int l16 = lane & 15, quad = lane >> 4;

    __shared__ ushort sK[64 * 72];   // [dk][l], stride 72 ushorts
    __shared__ ushort sV[64 * 72];   // [dv][l]

    const int grp = tid >> 7;        // 0 => K (exp), 1 => V
    const int st  = tid & 127;
    const int sc8 = (st & 7) * 8;    // c base 0..56
    const int sl4 = (st >> 3) * 4;   // l base 0..60
    const ushort* gsrc = (grp ? vv : kk)
        + ((size_t)(b * L_ + l0 + sl4)) * C_ + h * 64 + sc8;
    ushort* dst = grp ? sV : sK;

    float2 cst[8];
#pragma unroll
    for (int i = 0; i < 8; ++i)
        cst[i] = minv[(size_t)b * C_ + h * 64 + sc8 + i];

    f32x4_t acc[4];
#pragma unroll
    for (int j = 0; j < 4; ++j) acc[j] = (f32x4_t){0.f, 0.f, 0.f, 0.f};

    for (int tile = 0; tile < 4; ++tile) {
        u16x8 vr[4];
#pragma unroll
        for (int j = 0; j < 4; ++j)
            vr[j] = *(const u16x8*)(gsrc + ((size_t)(tile * 64 + j)) * C_);
        __syncthreads();              // prior tile's frag reads complete
        if (grp == 0) {
#pragma unroll
            for (int c = 0; c < 8; ++c) {
                u16x4 o;
#pragma unroll
                for (int j = 0; j < 4; ++j)
                    o[j] = f2bf(__expf(bf2f(vr[j][c]) - cst[c].x) * cst[c].y);
                *(u16x4*)(dst + (sc8 + c) * 72 + sl4) = o;
            }
        } else {
#pragma unroll
            for (int c = 0; c < 8; ++c) {
                u16x4 o;
#pragma unroll
                for (int j = 0; j < 4; ++j) o[j] = vr[j][c];
                *(u16x4*)(dst + (sc8 + c) * 72 + sl4) = o;
            }
        }
        __syncthreads();
#pragma unroll
        for (int k0 = 0; k0 < 64; k0 += 32) {
            const bf16x8_t vf = *(const bf16x8_t*)(sV + (w * 16 + l16) * 72 + k0 + quad * 8);
#pragma unroll
            for (int j = 0; j < 4; ++j) {
                const bf16x8_t kf = *(const bf16x8_t*)(sK + (j * 16 + l16) * 72 + k0 + quad * 8);
                acc[j] = __builtin_amdgcn_mfma_f32_16x16x32_bf16(vf, kf, acc[j], 0, 0, 0);
            }
        }
    }
    // acc[j][r]: dv = w*16 + quad*4 + r, dk = j*16 + l16
    float* cp = ctx + (size_t)bh * 4096;
#pragma unroll
    for (int j = 0; j < 4; ++j)
#pragma unroll
        for (int r = 0; r < 4; ++r)
            atomicAdd(&cp[(w * 16 + quad * 4 + r) * 64 + (j * 16 + l16)], acc[j][r]);
}

// ---------------------------------------------------------------------------
// att_mfma: att[b,l,h*64+dv] = sum_dk softmax_q[...dk] * ctxT[bh][dv][dk]
// q is RAW logits; per-row softmax over 64 dk fused into the staging loop
// (8 lanes/row shuffle-reduce). grid (L/128, B*H), 256 thr.
// ---------------------------------------------------------------------------
__global__ __launch_bounds__(256) void att_mfma(
    const ushort* __restrict__ q, const float* __restrict__ ctx,
    ushort* __restrict__ att)
{
    const int bh = blockIdx.y, b = bh >> 3, h = bh & 7;
    const int l0 = blockIdx.x * 128;
    const int tid = threadIdx.x, w = tid >> 6, lane = tid & 63;
    const int l16 = lane & 15, quad = lane >> 4;

    __shared__ ushort sQ[128 * 72];   // [l][dk]
    __shared__ ushort sC[64 * 72];    // [dv][dk]

    {
        const int part = tid & 7;
#pragma unroll
        for (int rr = tid >> 3; rr < 128; rr += 32) {
            u16x8 v = *(const u16x8*)(q + ((size_t)(b * L_ + l0 + rr)) * C_ + h * 64 + part * 8);
            float f[8], m = -3.0e38f;
#pragma unroll
            for (int i = 0; i < 8; ++i) { f[i] = bf2f(v[i]); m = fmaxf(m, f[i]); }
            m = fmaxf(m, __shfl_xor(m, 1));
            m = fmaxf(m, __shfl_xor(m, 2));
            m = fmaxf(m, __shfl_xor(m, 4));
            float s = 0.f;
#pragma unroll
            for (int i = 0; i < 8; ++i) { f[i] = __expf(f[i] - m); s += f[i]; }
            s += __shfl_xor(s, 1); s += __shfl_xor(s, 2); s += __shfl_xor(s, 4);
            const float inv = 1.f / s;
            u16x8 o;
#pragma unroll
            for (int i = 0; i < 8; ++i) o[i] = f2bf(f[i] * inv);
            *(u16x8*)(sQ + rr * 72 + part * 8) = o;
        }
        const int dv = tid >> 2, dk0 = (tid & 3) * 16;
        const float* cp = ctx + (size_t)bh * 4096 + dv * 64 + dk0;
#pragma unroll
        for (int i = 0; i < 16; ++i) sC[dv * 72 + dk0 + i] = f2bf(cp[i]);
    }
    __syncthreads();

    f32x4_t acc[2][4];
#pragma unroll
    for (int i = 0; i < 2; ++i)
#pragma unroll
        for (int j = 0; j < 4; ++j) acc[i][j] = (f32x4_t){0.f, 0.f, 0.f, 0.f};

#pragma unroll
    for (int ks = 0; ks < 2; ++ks) {
        const int k0 = ks * 32;
        bf16x8_t aq[2], bc[4];
#pragma unroll
        for (int i = 0; i < 2; ++i)
            aq[i] = *(const bf16x8_t*)(sQ + (w * 32 + i * 16 + l16) * 72 + k0 + quad * 8);
#pragma unroll
        for (int j = 0; j < 4; ++j)
            bc[j] = *(const bf16x8_t*)(sC + (j * 16 + l16) * 72 + k0 + quad * 8);
#pragma unroll
        for (int i = 0; i < 2; ++i)
#pragma unroll
            for (int j = 0; j < 4; ++j)
                acc[i][j] = __builtin_amdgcn_mfma_f32_16x16x32_bf16(aq[i], bc[j], acc[i][j], 0, 0, 0);
    }

#pragma unroll
    for (int j = 0; j < 4; ++j)
#pragma unroll
        for (int i = 0; i < 2; ++i) {
            const int mb = l0 + w * 32 + i * 16 + quad * 4;
#pragma unroll
            for (int r = 0; r < 4; ++r)
                att[((size_t)(b * L_ + mb + r)) * C_ + h * 64 + j * 16 + l16] = f2bf(acc[i][j][r]);
        }
}

// ---------------------------------------------------------------------------
// LayerNorm over 512 contiguous channels; wave per row.
// ---------------------------------------------------------------------------
template<bool OUTF32>
__global__ __launch_bounds__(256) void ln_row(
    const ushort* __restrict__ in, const float* __restrict__ g,
    const float* __restrict__ be, ushort* __restrict__ outb,
    float* __restrict__ outf)
{
    const int tid = threadIdx.x, w = tid >> 6, lane = tid & 63;
    const size_t row = (size_t)blockIdx.x * 4 + w;
    const ushort* p = in + row * C_ + lane * 8;
    u16x8 v = *(const u16x8*)p;
    float f[8], s = 0.f, s2 = 0.f;
#pragma unroll
    for (int i = 0; i < 8; ++i) { f[i] = bf2f(v[i]); s += f[i]; s2 = fmaf(f[i], f[i], s2); }
#pragma unroll
    for (int o = 1; o < 64; o <<= 1) { s += __shfl_xor(s, o); s2 += __shfl_xor(s2, o); }
    const float mean = s * (1.f / C_);
    const float var  = s2 * (1.f / C_) - mean * mean;
    const float inv  = rsqrtf(var + 1e-5f);
    if (OUTF32) {
        float* op = outf + row * C_ + lane * 8;
#pragma unroll
        for (int i = 0; i < 8; ++i)
            op[i] = (f[i] - mean) * inv * g[lane * 8 + i] + be[lane * 8 + i];
    } else {
        u16x8 ov;
#pragma unroll
        for (int i = 0; i < 8; ++i)
            ov[i] = f2bf((f[i] - mean) * inv * g[lane * 8 + i] + be[lane * 8 + i]);
        *(u16x8*)(outb + row * C_ + lane * 8) = ov;
    }
}

// ---------------------------------------------------------------------------
extern "C" void kernel_launch(void* const* d_in, const int* in_sizes, int n_in,
                              void* d_out, int out_size, void* d_ws, size_t ws_size,
                              hipStream_t stream)
{
    const float* z1  = (const float*)d_in[0];
    const float* z2  = (const float*)d_in[1];
    const float* Wq  = (const float*)d_in[2];
    const float* bq  = (const float*)d_in[3];
    const float* Wk  = (const float*)d_in[4];
    const float* bk  = (const float*)d_in[5];
    const float* Wv  = (const float*)d_in[6];
    const float* bv  = (const float*)d_in[7];
    const float* Wr  = (const float*)d_in[8];
    const float* br  = (const float*)d_in[9];
    const float* g1  = (const float*)d_in[10];
    const float* be1 = (const float*)d_in[11];
    const float* W1  = (const float*)d_in[12];
    const float* b1  = (const float*)d_in[13];
    const float* W2  = (const float*)d_in[14];
    const float* b2  = (const float*)d_in[15];
    const float* g2  = (const float*)d_in[16];
    const float* be2 = (const float*)d_in[17];
    float* out = (float*)d_out;

    const size_t SB = (size_t)B_ * L_ * C_;     // 16.78M elems per bf16 buffer
    ushort* ws16 = (ushort*)d_ws;
    ushort* b0v = ws16;            // z1t -> y
    ushort* b1v = ws16 + SB;       // z2t -> att
    ushort* b2v = ws16 + 2 * SB;   // q(raw) -> z -> yf32(lo)
    ushort* b3v = ws16 + 3 * SB;   // k(raw) -> x -> yf32(hi)
    ushort* wb  = ws16 + 4 * SB;   // bf16 weights (4MB)
    ushort* wbq = wb;
    ushort* wbk = wb + 262144;
    ushort* wbv = wb + 524288;
    ushort* wbr = wb + 786432;
    ushort* wb1 = wb + 1048576;
    ushort* wb2 = wb + 1572864;
    float*  ctxf = (float*)(wb + 2097152);       // [B*H,64,64] fp32 (256KB)
    float2* stats = (float2*)(ctxf + 65536);     // [B*C][8] (256KB)
    float2* minv  = stats + (size_t)B_ * C_ * 8; // [B*C] (32KB)
    ushort* vbuf = (ushort*)d_out;               // v lives in d_out
    ushort* hbuf = (ushort*)d_out;               // h: [B*L, 1024] bf16
    float*  yf32 = (float*)b2v;                  // spans b2v+b3v

    const dim3 blk(256);
    const dim3 blk512(512);
    const int M = B_ * L_;   // 32768

    // 0) input transposes + weight casts
    transpose_in<<<dim3(L_/64, C_/64, B_), blk, 0, stream>>>(z1, b0v);
    transpose_in<<<dim3(L_/64, C_/64, B_), blk, 0, stream>>>(z2, b1v);
    cvt_bf16<<<dim3(262144/4/256), blk, 0, stream>>>(Wq, wbq, 262144/4);
    cvt_bf16<<<dim3(262144/4/256), blk, 0, stream>>>(Wk, wbk, 262144/4);
    cvt_bf16<<<dim3(262144/4/256), blk, 0, stream>>>(Wv, wbv, 262144/4);
    cvt_bf16<<<dim3(262144/4/256), blk, 0, stream>>>(Wr, wbr, 262144/4);
    cvt_bf16<<<dim3(524288/4/256), blk, 0, stream>>>(W1, wb1, 524288/4);
    cvt_bf16<<<dim3(524288/4/256), blk, 0, stream>>>(W2, wb2, 524288/4);

    // 1) projections (MFMA); q and k stay RAW logits
    conv_mfma<0,false><<<dim3(M/256, C_/256), blk512, 0, stream>>>(b0v, wbq, bq, nullptr, b2v, M, C_, C_);
    conv_mfma<0,false><<<dim3(M/256, C_/256), blk512, 0, stream>>>(b1v, wbk, bk, nullptr, b3v, M, C_, C_);
    conv_mfma<0,false><<<dim3(M/256, C_/256), blk512, 0, stream>>>(b1v, wbv, bv, nullptr, vbuf, M, C_, C_);

    // 2) k-softmax stats (parallel, chunked)
    kstat_chunk<<<dim3(C_/64, B_ * 8), blk, 0, stream>>>(b3v, stats);
    kstat_merge<<<dim3((B_ * C_ + 255) / 256), blk, 0, stream>>>(stats, minv);

    // 3) ctxT = V^T softmax(K)  (softmax fused, MFMA, fp32 atomics, 16 l-splits)
    zero_kernel<<<dim3(65536/256), blk, 0, stream>>>(ctxf, 65536);
    ctx_mfma<<<dim3(16, B_ * H_), blk, 0, stream>>>(b3v, vbuf, minv, ctxf);

    // 4) att = softmax(q) . ctxT^T per head (q-softmax fused); att -> b1v
    att_mfma<<<dim3(L_/128, B_ * H_), blk, 0, stream>>>(b2v, ctxf, b1v);

    // 5) z = Wr@att + br + z1t  -> b2v (q dead)
    conv_mfma<0,true><<<dim3(M/256, C_/256), blk512, 0, stream>>>(b1v, wbr, br, b0v, b2v, M, C_, C_);

    // 6) x = LN1(z) -> b3v (k dead)
    ln_row<false><<<dim3(M/4), blk, 0, stream>>>(b2v, g1, be1, b3v, nullptr);

    // 7) h = ELU(W1@x) -> d_out (v dead)
    conv_mfma<1,false><<<dim3(M/256, C2_/256), blk512, 0, stream>>>(b3v, wb1, b1, nullptr, hbuf, M, C2_, C_);

    // 8) y = W2@h -> b0v (z1t dead)
    conv_mfma<0,false><<<dim3(M/256, C_/256), blk512, 0, stream>>>(hbuf, wb2, b2, nullptr, b0v, M, C_, C2_);

    // 9) LN2 -> fp32 [B*L,C] into b2v+b3v region (z,x dead)
    ln_row<true><<<dim3(M/4), blk, 0, stream>>>(b0v, g2, be2, nullptr, yf32);

    // 10) transpose to [B,C,L] fp32 -> d_out (h dead)
    transpose_out<<<dim3(L_/64, C_/64, B_), blk, 0, stream>>>(yf32, out);
}

// Round 5
// 506.523 us; speedup vs baseline: 1.1433x; 1.0256x over previous
//
#include <hip/hip_runtime.h>
#include <math.h>

#define B_   8
#define C_   512
#define L_   4096
#define H_   8
#define DK_  64
#define C2_  1024

typedef unsigned short ushort;
typedef short     bf16x8_t __attribute__((ext_vector_type(8)));
typedef float     f32x4_t  __attribute__((ext_vector_type(4)));
typedef unsigned short u16x8 __attribute__((ext_vector_type(8)));
typedef unsigned short u16x4 __attribute__((ext_vector_type(4)));

__device__ __forceinline__ float bf2f(ushort u) {
    unsigned int x = ((unsigned int)u) << 16;
    float f; __builtin_memcpy(&f, &x, 4); return f;
}
__device__ __forceinline__ ushort f2bf(float f) {
    unsigned int x; __builtin_memcpy(&x, &f, 4);
    x = (x + 0x7FFFu + ((x >> 16) & 1u)) >> 16;   // RNE
    return (ushort)x;
}

#define GLOAD_LDS16(gp, lp) \
    __builtin_amdgcn_global_load_lds((const __attribute__((address_space(1))) void*)(gp), \
                                     (__attribute__((address_space(3))) void*)(lp), 16, 0, 0)

// ---------------------------------------------------------------------------
// transpose_in: fp32 [B,C,L] -> bf16 [B*L, C].  grid (L/64, C/64, B), 256 thr
// ---------------------------------------------------------------------------
__global__ __launch_bounds__(256) void transpose_in(const float* __restrict__ in,
                                                    ushort* __restrict__ out)
{
    const int b = blockIdx.z, c0 = blockIdx.y * 64, l0 = blockIdx.x * 64;
    __shared__ float t[64][65];
    const int tid = threadIdx.x;
    {
        const int c = tid >> 4, l4 = (tid & 15) * 4;
        const float* ip = in + ((size_t)b * C_ + c0) * L_ + l0;
#pragma unroll
        for (int cc = c; cc < 64; cc += 16) {
            float4 v = *(const float4*)(ip + (size_t)cc * L_ + l4);
            t[l4 + 0][cc] = v.x; t[l4 + 1][cc] = v.y;
            t[l4 + 2][cc] = v.z; t[l4 + 3][cc] = v.w;
        }
    }
    __syncthreads();
    {
        const int l = tid >> 3, c8 = (tid & 7) * 8;
        ushort* op = out + ((size_t)b * L_ + l0) * C_ + c0;
#pragma unroll
        for (int ll = l; ll < 64; ll += 32) {
            u16x8 v;
#pragma unroll
            for (int i = 0; i < 8; ++i) v[i] = f2bf(t[ll][c8 + i]);
            *(u16x8*)(op + (size_t)ll * C_ + c8) = v;
        }
    }
}

// ---------------------------------------------------------------------------
// transpose_out: fp32 [B*L, C] -> fp32 [B,C,L].  grid (L/64, C/64, B)
// ---------------------------------------------------------------------------
__global__ __launch_bounds__(256) void transpose_out(const float* __restrict__ in,
                                                     float* __restrict__ out)
{
    const int b = blockIdx.z, c0 = blockIdx.y * 64, l0 = blockIdx.x * 64;
    __shared__ float t[64][65];   // t[c][l]
    const int tid = threadIdx.x;
    {
        const int l = tid >> 4, c4 = (tid & 15) * 4;
#pragma unroll
        for (int ll = l; ll < 64; ll += 16) {
            float4 v = *(const float4*)(in + ((size_t)(b * L_ + l0 + ll)) * C_ + c0 + c4);
            t[c4 + 0][ll] = v.x; t[c4 + 1][ll] = v.y;
            t[c4 + 2][ll] = v.z; t[c4 + 3][ll] = v.w;
        }
    }
    __syncthreads();
    {
        const int c = tid >> 4, l4 = (tid & 15) * 4;
        float* op = out + ((size_t)b * C_ + c0) * L_ + l0;
#pragma unroll
        for (int cc = c; cc < 64; cc += 16) {
            float4 v = {t[cc][l4], t[cc][l4 + 1], t[cc][l4 + 2], t[cc][l4 + 3]};
            *(float4*)(op + (size_t)cc * L_ + l4) = v;
        }
    }
}

__global__ __launch_bounds__(256) void cvt_bf16(const float* __restrict__ in,
                                                ushort* __restrict__ out, int n4)
{
    const int i = blockIdx.x * 256 + threadIdx.x;
    if (i < n4) {
        float4 v = *(const float4*)(in + 4 * (size_t)i);
        u16x4 o; o[0] = f2bf(v.x); o[1] = f2bf(v.y); o[2] = f2bf(v.z); o[3] = f2bf(v.w);
        *(u16x4*)(out + 4 * (size_t)i) = o;
    }
}

__global__ __launch_bounds__(256) void zero_kernel(float* __restrict__ p, int n4)
{
    const int i = blockIdx.x * 256 + threadIdx.x;
    if (i < n4) { float4 z = {0.f, 0.f, 0.f, 0.f}; *(float4*)(p + 4 * (size_t)i) = z; }
}

// ---------------------------------------------------------------------------
// conv_mfma: out[m,n] = act( sum_k A[m,k]*W[n,k] + bias[n] (+res[m,n]) )
// 128m x 256n tile, BK=32, 8 waves (2m x 4n; 64x64 out per wave).
// m230-form 2-phase single-barrier loop:
//   { STAGE(t+1)  [3 global_load_lds/thread, issued FIRST so the HBM latency
//     hides under this tile's compute] ; ds_read frags + 16 MFMA(t) ;
//     __syncthreads() [= vmcnt(0)+lgkmcnt(0)+s_barrier: certifies tile t+1
//     resident for next iter AND closes all readers of the buffer about to
//     be overwritten] }.
// ONE barrier per K-step.  __launch_bounds__(512,4) forces 2 blocks/CU
// (VGPR<=128) so inter-block overlap covers the drain.
// Slot swizzle (slot ^ (row&3) ^ ((row>>2)&3)) folded into the pre-swizzled
// global source and the frag read -> ~2-way max on ds_read_b128.
// Epilogue: mfma(wf, af) => lane owns 4 consecutive n; per-wave 64x72 LDS
// staging -> coalesced u16x8 stores (verified R1 pattern).
// ---------------------------------------------------------------------------
template<int ACT, bool HAS_RES>
__global__ __launch_bounds__(512, 4) void conv_mfma(
    const ushort* __restrict__ A, const ushort* __restrict__ Wt,
    const float* __restrict__ bias, const ushort* __restrict__ res,
    ushort* __restrict__ out, int M, int N, int K)
{
    const int m0 = blockIdx.x * 128;
    const int n0 = blockIdx.y * 256;
    const int tid = threadIdx.x;
    const int w = tid >> 6, lane = tid & 63;
    const int wm = (w >> 2) * 64, wn = (w & 3) * 64;
    const int l16 = lane & 15, quad = lane >> 4;

    // 72 KB: dbuf 2 x (A 4096 ush | B 8192 ush) = 24576 ush (48 KB);
    // epilogue reuses 8 x 4608 ush = 36864 ush (72 KB).
    __shared__ ushort smem[36864];

    // ---- staging sources (pre-swizzled global, linear LDS dest) ----
    // A-tile 128x32 (1 sweep): chunk=tid -> row=tid>>2, slot=tid&3
    const int rowA = tid >> 2, slotA = tid & 3;
    const int gsA = slotA ^ (rowA & 3) ^ ((rowA >> 2) & 3);
    const ushort* gA = A + (size_t)(m0 + rowA) * K + gsA * 8;
    // B-tile 256x32 (2 sweeps): sweep s covers rows s*128 + tid>>2
    const int rowB0 = tid >> 2, rowB1 = 128 + (tid >> 2), slotB = tid & 3;
    const int gsB0 = slotB ^ (rowB0 & 3) ^ ((rowB0 >> 2) & 3);
    const int gsB1 = slotB ^ (rowB1 & 3) ^ ((rowB1 >> 2) & 3);
    const ushort* gB0 = Wt + (size_t)(n0 + rowB0) * K + gsB0 * 8;
    const ushort* gB1 = Wt + (size_t)(n0 + rowB1) * K + gsB1 * 8;

    f32x4_t acc[4][4];
#pragma unroll
    for (int i = 0; i < 4; ++i)
#pragma unroll
        for (int j = 0; j < 4; ++j) acc[i][j] = (f32x4_t){0.f, 0.f, 0.f, 0.f};

    const int nt = K >> 5;

#define STAGE_T(ko_, boff_) do { \
        GLOAD_LDS16(gA + (ko_), smem + (boff_) + tid * 8); \
        GLOAD_LDS16(gB0 + (ko_), smem + (boff_) + 4096 + tid * 8); \
        GLOAD_LDS16(gB1 + (ko_), smem + (boff_) + 8192 + tid * 8); \
    } while (0)

    // prologue: tile 0 -> buf 0
    STAGE_T(0, 0);
    __syncthreads();

    for (int t = 0; t < nt; ++t) {
        const int cb = (t & 1) * 12288;
        if (t + 1 < nt) STAGE_T((t + 1) * 32, 12288 - cb);

        const ushort* bA = smem + cb;
        const ushort* bB = bA + 4096;
        bf16x8_t wf[4];
#pragma unroll
        for (int j = 0; j < 4; ++j) {
            const int rw = wn + j * 16 + l16;
            const int pw = quad ^ (rw & 3) ^ ((rw >> 2) & 3);
            wf[j] = *(const bf16x8_t*)(bB + rw * 32 + pw * 8);
        }
        __builtin_amdgcn_s_setprio(1);
#pragma unroll
        for (int i = 0; i < 4; ++i) {
            const int ra = wm + i * 16 + l16;
            const int pa = quad ^ (ra & 3) ^ ((ra >> 2) & 3);
            const bf16x8_t af = *(const bf16x8_t*)(bA + ra * 32 + pa * 8);
#pragma unroll
            for (int j = 0; j < 4; ++j)
                acc[i][j] = __builtin_amdgcn_mfma_f32_16x16x32_bf16(wf[j], af, acc[i][j], 0, 0, 0);
        }
        __builtin_amdgcn_s_setprio(0);
        __syncthreads();   // vmcnt(0)+lgkmcnt(0)+barrier: publishes tile t+1
    }
#undef STAGE_T

    // ---- epilogue ----
    // acc[i][j][r] = C[m0+wm+i*16+l16][n0+wn+j*16+quad*4+r]
    ushort* sT = smem + w * 4608;        // 64*72 ushorts per wave (private)
#pragma unroll
    for (int j = 0; j < 4; ++j) {
        const int nb4 = wn + j * 16 + quad * 4;          // block-local n
        const float4 bo = *(const float4*)(bias + n0 + nb4);
        const float bv[4] = {bo.x, bo.y, bo.z, bo.w};
#pragma unroll
        for (int i = 0; i < 4; ++i) {
            const int ml = i * 16 + l16;                 // wave-local m row
            const int m = m0 + wm + ml;
            float v[4];
#pragma unroll
            for (int r = 0; r < 4; ++r) v[r] = acc[i][j][r] + bv[r];
            if (HAS_RES) {
                const u16x4 rv = *(const u16x4*)(res + (size_t)m * N + n0 + nb4);
#pragma unroll
                for (int r = 0; r < 4; ++r) v[r] += bf2f(rv[r]);
            }
            if (ACT == 1) {
#pragma unroll
                for (int r = 0; r < 4; ++r) v[r] = (v[r] > 0.f) ? v[r] : (__expf(v[r]) - 1.f);
            }
            u16x4 pv;
#pragma unroll
            for (int r = 0; r < 4; ++r) pv[r] = f2bf(v[r]);
            *(u16x4*)(sT + ml * 72 + (nb4 - wn)) = pv;
        }
    }
    // same-wave readback (wave-private region, no barrier needed)
    {
        const int rr = lane >> 3, ch = lane & 7;
#pragma unroll
        for (int rep = 0; rep < 8; ++rep) {
            const int ml = rep * 8 + rr;
            const u16x8 vo = *(const u16x8*)(sT + ml * 72 + ch * 8);
            *(u16x8*)(out + (size_t)(m0 + wm + ml) * N + n0 + wn + ch * 8) = vo;
        }
    }
}

// ---------------------------------------------------------------------------
// kstat_chunk: per-chunk column (max, expsum) of k [B*L, C] bf16.
// grid (C/64, B*8), 256 thr. Chunk = 512 rows. stats[b*C+c][ch] float2.
// ---------------------------------------------------------------------------
__global__ __launch_bounds__(256) void kstat_chunk(const ushort* __restrict__ k,
                                                   float2* __restrict__ stats)
{
    const int cg = blockIdx.x;            // col group (64 cols)
    const int bc = blockIdx.y;            // b*8 + ch
    const int b = bc >> 3, ch = bc & 7;
    const int tid = threadIdx.x;
    const int g = tid & 7;                // 8-col subgroup
    const int kk = tid >> 3;              // 0..31 row worker
    const int w = tid >> 6, lane = tid & 63;
    const ushort* base = k + ((size_t)(b * L_) + ch * 512) * C_ + cg * 64 + g * 8;

    __shared__ float red[4][8][8];
    __shared__ float mcol[64];

    float fm[8];
#pragma unroll
    for (int i = 0; i < 8; ++i) fm[i] = -3.0e38f;
    for (int r = kk; r < 512; r += 32) {
        u16x8 v = *(const u16x8*)(base + (size_t)r * C_);
#pragma unroll
        for (int i = 0; i < 8; ++i) fm[i] = fmaxf(fm[i], bf2f(v[i]));
    }
#pragma unroll
    for (int off = 8; off <= 32; off <<= 1)
#pragma unroll
        for (int i = 0; i < 8; ++i) fm[i] = fmaxf(fm[i], __shfl_xor(fm[i], off));
    if ((lane >> 3) == 0)
#pragma unroll
        for (int i = 0; i < 8; ++i) red[w][g][i] = fm[i];
    __syncthreads();
    if (tid < 64) {
        const int g2 = tid >> 3, j = tid & 7;
        mcol[g2 * 8 + j] = fmaxf(fmaxf(red[0][g2][j], red[1][g2][j]),
                                 fmaxf(red[2][g2][j], red[3][g2][j]));
    }
    __syncthreads();
    float fmc[8];
#pragma unroll
    for (int i = 0; i < 8; ++i) fmc[i] = mcol[g * 8 + i];

    float fs[8] = {};
    for (int r = kk; r < 512; r += 32) {
        u16x8 v = *(const u16x8*)(base + (size_t)r * C_);
#pragma unroll
        for (int i = 0; i < 8; ++i) fs[i] += __expf(bf2f(v[i]) - fmc[i]);
    }
#pragma unroll
    for (int off = 8; off <= 32; off <<= 1)
#pragma unroll
        for (int i = 0; i < 8; ++i) fs[i] += __shfl_xor(fs[i], off);
    __syncthreads();
    if ((lane >> 3) == 0)
#pragma unroll
        for (int i = 0; i < 8; ++i) red[w][g][i] = fs[i];
    __syncthreads();
    if (tid < 64) {
        const int g2 = tid >> 3, j = tid & 7;
        const float s = red[0][g2][j] + red[1][g2][j] + red[2][g2][j] + red[3][g2][j];
        const int c = cg * 64 + g2 * 8 + j;
        stats[((size_t)(b * C_ + c)) * 8 + ch] = make_float2(mcol[g2 * 8 + j], s);
    }
}

// ---------------------------------------------------------------------------
// kstat_merge: global (m, 1/S) per (b,c) from 8 chunk stats.
// ---------------------------------------------------------------------------
__global__ __launch_bounds__(256) void kstat_merge(const float2* __restrict__ stats,
                                                   float2* __restrict__ minv)
{
    const int i = blockIdx.x * 256 + threadIdx.x;
    if (i >= B_ * C_) return;
    float2 st[8];
    float m = -3.0e38f;
#pragma unroll
    for (int ch = 0; ch < 8; ++ch) { st[ch] = stats[(size_t)i * 8 + ch]; m = fmaxf(m, st[ch].x); }
    float s = 0.f;
#pragma unroll
    for (int ch = 0; ch < 8; ++ch) s += st[ch].y * __expf(st[ch].x - m);
    minv[i] = make_float2(m, 1.f / s);
}

// ---------------------------------------------------------------------------
// ctx_mfma: ctxT[bh][dv][dk] += sum_l V[l][dv] * softmaxK[l][dk]  via MFMA.
// K (exp applied, bf16) and V staged TRANSPOSED [c][l] in LDS (stride 72);
// wave w computes dv rows [w*16, w*16+16) with mfma(vf, kf): D-row <-> first
// operand (harness-verified convention). grid (16, B*H), 256 thr.
// Threads 0..127 stage K (exp), 128..255 stage V (transpose passthrough).
// ---------------------------------------------------------------------------
__global__ __launch_bounds__(256) void ctx_mfma(
    const ushort* __restrict__ kk, const ushort* __restrict__ vv,
    const float2* __restrict__ minv, float* __restrict__ ctx)
{
    const int bh = blockIdx.y, b = bh >> 3, h = bh & 7;
    const int l0 = blockIdx.x * 256;
    const int tid = threadIdx.x, w = tid >> 6, lane = tid & 63;
    const int l16 = lane & 15, quad = lane >> 4;

    __shared__ ushort sK[64 * 72];   // [dk][l], stride 72 ushorts
    __shared__ ushort sV[64 * 72];   // [dv][l]

    const int grp = tid >> 7;        // 0 => K (exp), 1 => V
    const int st  = tid & 127;
    const int sc8 = (st & 7) * 8;    // c base 0..56
    const int sl4 = (st >> 3) * 4;   // l base 0..60
    const ushort* gsrc = (grp ? vv : kk)
        + ((size_t)(b * L_ + l0 + sl4)) * C_ + h * 64 + sc8;
    ushort* dst = grp ? sV : sK;

    float2 cst[8];
#pragma unroll
    for (int i = 0; i < 8; ++i)
        cst[i] = minv[(size_t)b * C_ + h * 64 + sc8 + i];

    f32x4_t acc[4];
#pragma unroll
    for (int j = 0; j < 4; ++j) acc[j] = (f32x4_t){0.f, 0.f, 0.f, 0.f};

    for (int tile = 0; tile < 4; ++tile) {
        u16x8 vr[4];
#pragma unroll
        for (int j = 0; j < 4; ++j)
            vr[j] = *(const u16x8*)(gsrc + ((size_t)(tile * 64 + j)) * C_);
        __syncthreads();              // prior tile's frag reads complete
        if (grp == 0) {
#pragma unroll
            for (int c = 0; c < 8; ++c) {
                u16x4 o;
#pragma unroll
                for (int j = 0; j < 4; ++j)
                    o[j] = f2bf(__expf(bf2f(vr[j][c]) - cst[c].x) * cst[c].y);
                *(u16x4*)(dst + (sc8 + c) * 72 + sl4) = o;
            }
        } else {
#pragma unroll
            for (int c = 0; c < 8; ++c) {
                u16x4 o;
#pragma unroll
                for (int j = 0; j < 4; ++j) o[j] = vr[j][c];
                *(u16x4*)(dst + (sc8 + c) * 72 + sl4) = o;
            }
        }
        __syncthreads();
#pragma unroll
        for (int k0 = 0; k0 < 64; k0 += 32) {
            const bf16x8_t vf = *(const bf16x8_t*)(sV + (w * 16 + l16) * 72 + k0 + quad * 8);
#pragma unroll
            for (int j = 0; j < 4; ++j) {
                const bf16x8_t kf = *(const bf16x8_t*)(sK + (j * 16 + l16) * 72 + k0 + quad * 8);
                acc[j] = __builtin_amdgcn_mfma_f32_16x16x32_bf16(vf, kf, acc[j], 0, 0, 0);
            }
        }
    }
    // acc[j][r]: dv = w*16 + quad*4 + r, dk = j*16 + l16
    float* cp = ctx + (size_t)bh * 4096;
#pragma unroll
    for (int j = 0; j < 4; ++j)
#pragma unroll
        for (int r = 0; r < 4; ++r)
            atomicAdd(&cp[(w * 16 + quad * 4 + r) * 64 + (j * 16 + l16)], acc[j][r]);
}

// ---------------------------------------------------------------------------
// att_mfma: att[b,l,h*64+dv] = sum_dk softmax_q[...dk] * ctxT[bh][dv][dk]
// q is RAW logits; per-row softmax over 64 dk fused into the staging loop
// (8 lanes/row shuffle-reduce). grid (L/128, B*H), 256 thr.
// ---------------------------------------------------------------------------
__global__ __launch_bounds__(256) void att_mfma(
    const ushort* __restrict__ q, const float* __restrict__ ctx,
    ushort* __restrict__ att)
{
    const int bh = blockIdx.y, b = bh >> 3, h = bh & 7;
    const int l0 = blockIdx.x * 128;
    const int tid = threadIdx.x, w = tid >> 6, lane = tid & 63;
    const int l16 = lane & 15, quad = lane >> 4;

    __shared__ ushort sQ[128 * 72];   // [l][dk]
    __shared__ ushort sC[64 * 72];    // [dv][dk]

    {
        const int part = tid & 7;
#pragma unroll
        for (int rr = tid >> 3; rr < 128; rr += 32) {
            u16x8 v = *(const u16x8*)(q + ((size_t)(b * L_ + l0 + rr)) * C_ + h * 64 + part * 8);
            float f[8], m = -3.0e38f;
#pragma unroll
            for (int i = 0; i < 8; ++i) { f[i] = bf2f(v[i]); m = fmaxf(m, f[i]); }
            m = fmaxf(m, __shfl_xor(m, 1));
            m = fmaxf(m, __shfl_xor(m, 2));
            m = fmaxf(m, __shfl_xor(m, 4));
            float s = 0.f;
#pragma unroll
            for (int i = 0; i < 8; ++i) { f[i] = __expf(f[i] - m); s += f[i]; }
            s += __shfl_xor(s, 1); s += __shfl_xor(s, 2); s += __shfl_xor(s, 4);
            const float inv = 1.f / s;
            u16x8 o;
#pragma unroll
            for (int i = 0; i < 8; ++i) o[i] = f2bf(f[i] * inv);
            *(u16x8*)(sQ + rr * 72 + part * 8) = o;
        }
        const int dv = tid >> 2, dk0 = (tid & 3) * 16;
        const float* cp = ctx + (size_t)bh * 4096 + dv * 64 + dk0;
#pragma unroll
        for (int i = 0; i < 16; ++i) sC[dv * 72 + dk0 + i] = f2bf(cp[i]);
    }
    __syncthreads();

    f32x4_t acc[2][4];
#pragma unroll
    for (int i = 0; i < 2; ++i)
#pragma unroll
        for (int j = 0; j < 4; ++j) acc[i][j] = (f32x4_t){0.f, 0.f, 0.f, 0.f};

#pragma unroll
    for (int ks = 0; ks < 2; ++ks) {
        const int k0 = ks * 32;
        bf16x8_t aq[2], bc[4];
#pragma unroll
        for (int i = 0; i < 2; ++i)
            aq[i] = *(const bf16x8_t*)(sQ + (w * 32 + i * 16 + l16) * 72 + k0 + quad * 8);
#pragma unroll
        for (int j = 0; j < 4; ++j)
            bc[j] = *(const bf16x8_t*)(sC + (j * 16 + l16) * 72 + k0 + quad * 8);
#pragma unroll
        for (int i = 0; i < 2; ++i)
#pragma unroll
            for (int j = 0; j < 4; ++j)
                acc[i][j] = __builtin_amdgcn_mfma_f32_16x16x32_bf16(aq[i], bc[j], acc[i][j], 0, 0, 0);
    }

#pragma unroll
    for (int j = 0; j < 4; ++j)
#pragma unroll
        for (int i = 0; i < 2; ++i) {
            const int mb = l0 + w * 32 + i * 16 + quad * 4;
#pragma unroll
            for (int r = 0; r < 4; ++r)
                att[((size_t)(b * L_ + mb + r)) * C_ + h * 64 + j * 16 + l16] = f2bf(acc[i][j][r]);
        }
}

// ---------------------------------------------------------------------------
// LayerNorm over 512 contiguous channels; wave per row.
// ---------------------------------------------------------------------------
template<bool OUTF32>
__global__ __launch_bounds__(256) void ln_row(
    const ushort* __restrict__ in, const float* __restrict__ g,
    const float* __restrict__ be, ushort* __restrict__ outb,
    float* __restrict__ outf)
{
    const int tid = threadIdx.x, w = tid >> 6, lane = tid & 63;
    const size_t row = (size_t)blockIdx.x * 4 + w;
    const ushort* p = in + row * C_ + lane * 8;
    u16x8 v = *(const u16x8*)p;
    float f[8], s = 0.f, s2 = 0.f;
#pragma unroll
    for (int i = 0; i < 8; ++i) { f[i] = bf2f(v[i]); s += f[i]; s2 = fmaf(f[i], f[i], s2); }
#pragma unroll
    for (int o = 1; o < 64; o <<= 1) { s += __shfl_xor(s, o); s2 += __shfl_xor(s2, o); }
    const float mean = s * (1.f / C_);
    const float var  = s2 * (1.f / C_) - mean * mean;
    const float inv  = rsqrtf(var + 1e-5f);
    if (OUTF32) {
        float* op = outf + row * C_ + lane * 8;
#pragma unroll
        for (int i = 0; i < 8; ++i)
            op[i] = (f[i] - mean) * inv * g[lane * 8 + i] + be[lane * 8 + i];
    } else {
        u16x8 ov;
#pragma unroll
        for (int i = 0; i < 8; ++i)
            ov[i] = f2bf((f[i] - mean) * inv * g[lane * 8 + i] + be[lane * 8 + i]);
        *(u16x8*)(outb + row * C_ + lane * 8) = ov;
    }
}

// ---------------------------------------------------------------------------
extern "C" void kernel_launch(void* const* d_in, const int* in_sizes, int n_in,
                              void* d_out, int out_size, void* d_ws, size_t ws_size,
                              hipStream_t stream)
{
    const float* z1  = (const float*)d_in[0];
    const float* z2  = (const float*)d_in[1];
    const float* Wq  = (const float*)d_in[2];
    const float* bq  = (const float*)d_in[3];
    const float* Wk  = (const float*)d_in[4];
    const float* bk  = (const float*)d_in[5];
    const float* Wv  = (const float*)d_in[6];
    const float* bv  = (const float*)d_in[7];
    const float* Wr  = (const float*)d_in[8];
    const float* br  = (const float*)d_in[9];
    const float* g1  = (const float*)d_in[10];
    const float* be1 = (const float*)d_in[11];
    const float* W1  = (const float*)d_in[12];
    const float* b1  = (const float*)d_in[13];
    const float* W2  = (const float*)d_in[14];
    const float* b2  = (const float*)d_in[15];
    const float* g2  = (const float*)d_in[16];
    const float* be2 = (const float*)d_in[17];
    float* out = (float*)d_out;

    const size_t SB = (size_t)B_ * L_ * C_;     // 16.78M elems per bf16 buffer
    ushort* ws16 = (ushort*)d_ws;
    ushort* b0v = ws16;            // z1t -> y
    ushort* b1v = ws16 + SB;       // z2t -> att
    ushort* b2v = ws16 + 2 * SB;   // q(raw) -> z -> yf32(lo)
    ushort* b3v = ws16 + 3 * SB;   // k(raw) -> x -> yf32(hi)
    ushort* wb  = ws16 + 4 * SB;   // bf16 weights (4MB)
    ushort* wbq = wb;
    ushort* wbk = wb + 262144;
    ushort* wbv = wb + 524288;
    ushort* wbr = wb + 786432;
    ushort* wb1 = wb + 1048576;
    ushort* wb2 = wb + 1572864;
    float*  ctxf = (float*)(wb + 2097152);       // [B*H,64,64] fp32 (256KB)
    float2* stats = (float2*)(ctxf + 65536);     // [B*C][8] (256KB)
    float2* minv  = stats + (size_t)B_ * C_ * 8; // [B*C] (32KB)
    ushort* vbuf = (ushort*)d_out;               // v lives in d_out
    ushort* hbuf = (ushort*)d_out;               // h: [B*L, 1024] bf16
    float*  yf32 = (float*)b2v;                  // spans b2v+b3v

    const dim3 blk(256);
    const dim3 blk512(512);
    const int M = B_ * L_;   // 32768

    // 0) input transposes + weight casts
    transpose_in<<<dim3(L_/64, C_/64, B_), blk, 0, stream>>>(z1, b0v);
    transpose_in<<<dim3(L_/64, C_/64, B_), blk, 0, stream>>>(z2, b1v);
    cvt_bf16<<<dim3(262144/4/256), blk, 0, stream>>>(Wq, wbq, 262144/4);
    cvt_bf16<<<dim3(262144/4/256), blk, 0, stream>>>(Wk, wbk, 262144/4);
    cvt_bf16<<<dim3(262144/4/256), blk, 0, stream>>>(Wv, wbv, 262144/4);
    cvt_bf16<<<dim3(262144/4/256), blk, 0, stream>>>(Wr, wbr, 262144/4);
    cvt_bf16<<<dim3(524288/4/256), blk, 0, stream>>>(W1, wb1, 524288/4);
    cvt_bf16<<<dim3(524288/4/256), blk, 0, stream>>>(W2, wb2, 524288/4);

    // 1) projections (MFMA); q and k stay RAW logits
    conv_mfma<0,false><<<dim3(M/128, C_/256), blk512, 0, stream>>>(b0v, wbq, bq, nullptr, b2v, M, C_, C_);
    conv_mfma<0,false><<<dim3(M/128, C_/256), blk512, 0, stream>>>(b1v, wbk, bk, nullptr, b3v, M, C_, C_);
    conv_mfma<0,false><<<dim3(M/128, C_/256), blk512, 0, stream>>>(b1v, wbv, bv, nullptr, vbuf, M, C_, C_);

    // 2) k-softmax stats (parallel, chunked)
    kstat_chunk<<<dim3(C_/64, B_ * 8), blk, 0, stream>>>(b3v, stats);
    kstat_merge<<<dim3((B_ * C_ + 255) / 256), blk, 0, stream>>>(stats, minv);

    // 3) ctxT = V^T softmax(K)  (softmax fused, MFMA, fp32 atomics, 16 l-splits)
    zero_kernel<<<dim3(65536/256), blk, 0, stream>>>(ctxf, 65536);
    ctx_mfma<<<dim3(16, B_ * H_), blk, 0, stream>>>(b3v, vbuf, minv, ctxf);

    // 4) att = softmax(q) . ctxT^T per head (q-softmax fused); att -> b1v
    att_mfma<<<dim3(L_/128, B_ * H_), blk, 0, stream>>>(b2v, ctxf, b1v);

    // 5) z = Wr@att + br + z1t  -> b2v (q dead)
    conv_mfma<0,true><<<dim3(M/128, C_/256), blk512, 0, stream>>>(b1v, wbr, br, b0v, b2v, M, C_, C_);

    // 6) x = LN1(z) -> b3v (k dead)
    ln_row<false><<<dim3(M/4), blk, 0, stream>>>(b2v, g1, be1, b3v, nullptr);

    // 7) h = ELU(W1@x) -> d_out (v dead)
    conv_mfma<1,false><<<dim3(M/128, C2_/256), blk512, 0, stream>>>(b3v, wb1, b1, nullptr, hbuf, M, C2_, C_);

    // 8) y = W2@h -> b0v (z1t dead)
    conv_mfma<0,false><<<dim3(M/128, C_/256), blk512, 0, stream>>>(hbuf, wb2, b2, nullptr, b0v, M, C_, C2_);

    // 9) LN2 -> fp32 [B*L,C] into b2v+b3v region (z,x dead)
    ln_row<true><<<dim3(M/4), blk, 0, stream>>>(b0v, g2, be2, nullptr, yf32);

    // 10) transpose to [B,C,L] fp32 -> d_out (h dead)
    transpose_out<<<dim3(L_/64, C_/64, B_), blk, 0, stream>>>(yf32, out);
}

// Round 6
// 502.485 us; speedup vs baseline: 1.1525x; 1.0080x over previous
//
#include <hip/hip_runtime.h>
#include <math.h>

#define B_   8
#define C_   512
#define L_   4096
#define H_   8
#define DK_  64
#define C2_  1024

typedef unsigned short ushort;
typedef short     bf16x8_t __attribute__((ext_vector_type(8)));
typedef float     f32x4_t  __attribute__((ext_vector_type(4)));
typedef unsigned short u16x8 __attribute__((ext_vector_type(8)));
typedef unsigned short u16x4 __attribute__((ext_vector_type(4)));

__device__ __forceinline__ float bf2f(ushort u) {
    unsigned int x = ((unsigned int)u) << 16;
    float f; __builtin_memcpy(&f, &x, 4); return f;
}
__device__ __forceinline__ ushort f2bf(float f) {
    unsigned int x; __builtin_memcpy(&x, &f, 4);
    x = (x + 0x7FFFu + ((x >> 16) & 1u)) >> 16;   // RNE
    return (ushort)x;
}

#define GLOAD_LDS16(gp, lp) \
    __builtin_amdgcn_global_load_lds((const __attribute__((address_space(1))) void*)(gp), \
                                     (__attribute__((address_space(3))) void*)(lp), 16, 0, 0)

// ---------------------------------------------------------------------------
// transpose_in: fp32 [B,C,L] -> bf16 [B*L, C].  grid (L/64, C/64, B), 256 thr
// ---------------------------------------------------------------------------
__global__ __launch_bounds__(256) void transpose_in(const float* __restrict__ in,
                                                    ushort* __restrict__ out)
{
    const int b = blockIdx.z, c0 = blockIdx.y * 64, l0 = blockIdx.x * 64;
    __shared__ float t[64][65];
    const int tid = threadIdx.x;
    {
        const int c = tid >> 4, l4 = (tid & 15) * 4;
        const float* ip = in + ((size_t)b * C_ + c0) * L_ + l0;
#pragma unroll
        for (int cc = c; cc < 64; cc += 16) {
            float4 v = *(const float4*)(ip + (size_t)cc * L_ + l4);
            t[l4 + 0][cc] = v.x; t[l4 + 1][cc] = v.y;
            t[l4 + 2][cc] = v.z; t[l4 + 3][cc] = v.w;
        }
    }
    __syncthreads();
    {
        const int l = tid >> 3, c8 = (tid & 7) * 8;
        ushort* op = out + ((size_t)b * L_ + l0) * C_ + c0;
#pragma unroll
        for (int ll = l; ll < 64; ll += 32) {
            u16x8 v;
#pragma unroll
            for (int i = 0; i < 8; ++i) v[i] = f2bf(t[ll][c8 + i]);
            *(u16x8*)(op + (size_t)ll * C_ + c8) = v;
        }
    }
}

// ---------------------------------------------------------------------------
// transpose_out: fp32 [B*L, C] -> fp32 [B,C,L].  grid (L/64, C/64, B)
// ---------------------------------------------------------------------------
__global__ __launch_bounds__(256) void transpose_out(const float* __restrict__ in,
                                                     float* __restrict__ out)
{
    const int b = blockIdx.z, c0 = blockIdx.y * 64, l0 = blockIdx.x * 64;
    __shared__ float t[64][65];   // t[c][l]
    const int tid = threadIdx.x;
    {
        const int l = tid >> 4, c4 = (tid & 15) * 4;
#pragma unroll
        for (int ll = l; ll < 64; ll += 16) {
            float4 v = *(const float4*)(in + ((size_t)(b * L_ + l0 + ll)) * C_ + c0 + c4);
            t[c4 + 0][ll] = v.x; t[c4 + 1][ll] = v.y;
            t[c4 + 2][ll] = v.z; t[c4 + 3][ll] = v.w;
        }
    }
    __syncthreads();
    {
        const int c = tid >> 4, l4 = (tid & 15) * 4;
        float* op = out + ((size_t)b * C_ + c0) * L_ + l0;
#pragma unroll
        for (int cc = c; cc < 64; cc += 16) {
            float4 v = {t[cc][l4], t[cc][l4 + 1], t[cc][l4 + 2], t[cc][l4 + 3]};
            *(float4*)(op + (size_t)cc * L_ + l4) = v;
        }
    }
}

__global__ __launch_bounds__(256) void cvt_bf16(const float* __restrict__ in,
                                                ushort* __restrict__ out, int n4)
{
    const int i = blockIdx.x * 256 + threadIdx.x;
    if (i < n4) {
        float4 v = *(const float4*)(in + 4 * (size_t)i);
        u16x4 o; o[0] = f2bf(v.x); o[1] = f2bf(v.y); o[2] = f2bf(v.z); o[3] = f2bf(v.w);
        *(u16x4*)(out + 4 * (size_t)i) = o;
    }
}

__global__ __launch_bounds__(256) void zero_kernel(float* __restrict__ p, int n4)
{
    const int i = blockIdx.x * 256 + threadIdx.x;
    if (i < n4) { float4 z = {0.f, 0.f, 0.f, 0.f}; *(float4*)(p + 4 * (size_t)i) = z; }
}

// ---------------------------------------------------------------------------
// conv_mfma: out[m,n] = act( sum_k A[m,k]*W[n,k] + bias[n] (+res[m,n]) )
// 256x256 tile, BK=64, 8 waves (2m x 4n; per-wave 128m x 64n out).
// Phase schedule (T2+T3+T4+T5): 4 phases per K-tile, phase = quadrant
// (ksub, m-four).  Per phase:
//   { ds_read next quadrant's frags (BEFORE the barrier: latency hides under
//     other waves' MFMA) ; stage ONE half-tile (A0/A1/B0/B1) of tile T+1 ;
//     [phase 0 only: s_waitcnt vmcnt(2) -- certifies ALL 8 loads of tile T,
//     leaves the just-issued stage in flight; never drains except last tile]
//     ; s_barrier ; 16 MFMA under setprio(1) ; s_barrier }.
// Stage order A0,A1,B0,B1: A (HBM-latency) gets 3-4 phases of lead,
// B (L2-hot weights) needs only 1-2.
// LDS 128 KB: 2 bufs x (A[2 halves][128][64k] | B[2][128][64k]).
// Swizzle slot ^= ((row&1)<<2) ^ (((row>>2)&1)<<1)  (16B-slot units): moves
// data across the 64B k-halves so every frag read spreads uniformly over all
// 8 bank-quarters (enumerated).  Folded into pre-swizzled global source.
// Epilogue: lane owns 4 consecutive n; per-wave [64][72] LDS staging in two
// m-half passes -> coalesced u16x8 stores (verified R1 pattern).
// ---------------------------------------------------------------------------
template<int ACT, bool HAS_RES>
__global__ __launch_bounds__(512, 1) void conv_mfma(
    const ushort* __restrict__ A, const ushort* __restrict__ Wt,
    const float* __restrict__ bias, const ushort* __restrict__ res,
    ushort* __restrict__ out, int M, int N, int K)
{
    const int m0 = blockIdx.x * 256;
    const int n0 = blockIdx.y * 256;
    const int tid = threadIdx.x;
    const int w = tid >> 6, lane = tid & 63;
    const int wmh = w >> 2;              // wave's A half (0/1)
    const int wn = (w & 3) * 64;
    const int bhalf = (w & 3) >> 1;      // wave's B half
    const int brow0 = (w & 1) * 64;      // wave's row base within B half
    const int l16 = lane & 15, quad = lane >> 4;

    __shared__ ushort smem[65536];       // 128 KB

    // ---- staging thread mapping (pre-swizzled global source) ----
    const int rl = tid >> 3;             // 0..63
    const int sp = (tid & 7) ^ ((rl & 1) << 2) ^ (((rl >> 2) & 1) << 1);
    const ushort* gA[4]; const ushort* gB[4];
#pragma unroll
    for (int r4 = 0; r4 < 4; ++r4) {
        gA[r4] = A  + (size_t)(m0 + r4 * 64 + rl) * K + sp * 8;
        gB[r4] = Wt + (size_t)(n0 + r4 * 64 + rl) * K + sp * 8;
    }
    // half layout (ushort units): buf d: d*32768; A half h: h*8192;
    // B half h: 16384 + h*8192; within half: row*64 + slot*8; chunk1 +4096.
#define STAGE_A(h, kt, nbuf) do { \
        ushort* l0 = smem + (nbuf) + (h) * 8192 + tid * 8; \
        GLOAD_LDS16(gA[(h)*2]     + (size_t)(kt) * 64, l0); \
        GLOAD_LDS16(gA[(h)*2 + 1] + (size_t)(kt) * 64, l0 + 4096); \
    } while (0)
#define STAGE_B(h, kt, nbuf) do { \
        ushort* l0 = smem + (nbuf) + 16384 + (h) * 8192 + tid * 8; \
        GLOAD_LDS16(gB[(h)*2]     + (size_t)(kt) * 64, l0); \
        GLOAD_LDS16(gB[(h)*2 + 1] + (size_t)(kt) * 64, l0 + 4096); \
    } while (0)

    // ---- frag read constants ----
    const int fl  = ((l16 & 1) << 2) | (((l16 >> 2) & 1) << 1);
    const int sx0 = (0 * 4 + quad) ^ fl;          // ks=0 physical 16B slot
    const int sx1 = (1 * 4 + quad) ^ fl;          // ks=1

    f32x4_t acc[8][4];
#pragma unroll
    for (int i = 0; i < 8; ++i)
#pragma unroll
        for (int j = 0; j < 4; ++j) acc[i][j] = (f32x4_t){0.f, 0.f, 0.f, 0.f};

    const int nt = K >> 6;               // K-tiles of 64 (8 for K=512)

    // prologue: tile 0, halves A0,A1,B0,B1 (8 loads/thread in flight)
    STAGE_A(0, 0, 0); STAGE_A(1, 0, 0); STAGE_B(0, 0, 0); STAGE_B(1, 0, 0);

    for (int T = 0; T < nt; ++T) {
        const int cb = (T & 1) * 32768;
        const int nb = 32768 - cb;
        const bool pf = (T + 1 < nt);
        const ushort* aB = smem + cb + wmh * 8192;
        const ushort* bB = smem + cb + 16384 + bhalf * 8192 + brow0 * 64;
        bf16x8_t bfr[4], af[4];

        // ---- phase 0: (ks0, m-four 0) ----
        if (pf) STAGE_A(0, T + 1, nb);
        __builtin_amdgcn_sched_barrier(0);
        if (pf) { asm volatile("s_waitcnt vmcnt(2)" ::: "memory"); }
        else    { asm volatile("s_waitcnt vmcnt(0)" ::: "memory"); }
        __builtin_amdgcn_s_barrier();
        __builtin_amdgcn_sched_barrier(0);
#pragma unroll
        for (int j = 0; j < 4; ++j)
            bfr[j] = *(const bf16x8_t*)(bB + (j * 16 + l16) * 64 + sx0 * 8);
#pragma unroll
        for (int x = 0; x < 4; ++x)
            af[x] = *(const bf16x8_t*)(aB + (x * 16 + l16) * 64 + sx0 * 8);
        __builtin_amdgcn_s_setprio(1);
#pragma unroll
        for (int x = 0; x < 4; ++x)
#pragma unroll
            for (int j = 0; j < 4; ++j)
                acc[x][j] = __builtin_amdgcn_mfma_f32_16x16x32_bf16(bfr[j], af[x], acc[x][j], 0, 0, 0);
        __builtin_amdgcn_s_setprio(0);
        __builtin_amdgcn_s_barrier();

        // ---- phase 1: (ks0, m-four 1), B reused ----
#pragma unroll
        for (int x = 0; x < 4; ++x)
            af[x] = *(const bf16x8_t*)(aB + ((x + 4) * 16 + l16) * 64 + sx0 * 8);
        if (pf) STAGE_A(1, T + 1, nb);
        __builtin_amdgcn_s_barrier();
        __builtin_amdgcn_sched_barrier(0);
        __builtin_amdgcn_s_setprio(1);
#pragma unroll
        for (int x = 0; x < 4; ++x)
#pragma unroll
            for (int j = 0; j < 4; ++j)
                acc[x + 4][j] = __builtin_amdgcn_mfma_f32_16x16x32_bf16(bfr[j], af[x], acc[x + 4][j], 0, 0, 0);
        __builtin_amdgcn_s_setprio(0);
        __builtin_amdgcn_s_barrier();

        // ---- phase 2: (ks1, m-four 0) ----
#pragma unroll
        for (int j = 0; j < 4; ++j)
            bfr[j] = *(const bf16x8_t*)(bB + (j * 16 + l16) * 64 + sx1 * 8);
#pragma unroll
        for (int x = 0; x < 4; ++x)
            af[x] = *(const bf16x8_t*)(aB + (x * 16 + l16) * 64 + sx1 * 8);
        if (pf) STAGE_B(0, T + 1, nb);
        __builtin_amdgcn_s_barrier();
        __builtin_amdgcn_sched_barrier(0);
        __builtin_amdgcn_s_setprio(1);
#pragma unroll
        for (int x = 0; x < 4; ++x)
#pragma unroll
            for (int j = 0; j < 4; ++j)
                acc[x][j] = __builtin_amdgcn_mfma_f32_16x16x32_bf16(bfr[j], af[x], acc[x][j], 0, 0, 0);
        __builtin_amdgcn_s_setprio(0);
        __builtin_amdgcn_s_barrier();

        // ---- phase 3: (ks1, m-four 1), B reused ----
#pragma unroll
        for (int x = 0; x < 4; ++x)
            af[x] = *(const bf16x8_t*)(aB + ((x + 4) * 16 + l16) * 64 + sx1 * 8);
        if (pf) STAGE_B(1, T + 1, nb);
        __builtin_amdgcn_s_barrier();
        __builtin_amdgcn_sched_barrier(0);
        __builtin_amdgcn_s_setprio(1);
#pragma unroll
        for (int x = 0; x < 4; ++x)
#pragma unroll
            for (int j = 0; j < 4; ++j)
                acc[x + 4][j] = __builtin_amdgcn_mfma_f32_16x16x32_bf16(bfr[j], af[x], acc[x + 4][j], 0, 0, 0);
        __builtin_amdgcn_s_setprio(0);
        __builtin_amdgcn_s_barrier();
    }
#undef STAGE_A
#undef STAGE_B

    // ---- epilogue: two m-half passes, LDS-staged coalesced stores ----
    // acc[i][j][r] = C[m0 + wmh*128 + i*16 + l16][n0 + wn + j*16 + quad*4 + r]
    ushort* sT = smem + w * 4608;        // [64][72] ushorts per wave (private)
#pragma unroll
    for (int h2 = 0; h2 < 2; ++h2) {
#pragma unroll
        for (int j = 0; j < 4; ++j) {
            const int nb4 = wn + j * 16 + quad * 4;
            const float4 bo = *(const float4*)(bias + n0 + nb4);
            const float bv[4] = {bo.x, bo.y, bo.z, bo.w};
#pragma unroll
            for (int x = 0; x < 4; ++x) {
                const int ml = x * 16 + l16;
                const int m = m0 + wmh * 128 + h2 * 64 + ml;
                float v[4];
#pragma unroll
                for (int r = 0; r < 4; ++r) v[r] = acc[h2 * 4 + x][j][r] + bv[r];
                if (HAS_RES) {
                    const u16x4 rv = *(const u16x4*)(res + (size_t)m * N + n0 + nb4);
#pragma unroll
                    for (int r = 0; r < 4; ++r) v[r] += bf2f(rv[r]);
                }
                if (ACT == 1) {
#pragma unroll
                    for (int r = 0; r < 4; ++r) v[r] = (v[r] > 0.f) ? v[r] : (__expf(v[r]) - 1.f);
                }
                u16x4 pv;
#pragma unroll
                for (int r = 0; r < 4; ++r) pv[r] = f2bf(v[r]);
                *(u16x4*)(sT + ml * 72 + (nb4 - wn)) = pv;
            }
        }
        {
            const int rr = lane >> 3, ch = lane & 7;
#pragma unroll
            for (int rep = 0; rep < 8; ++rep) {
                const int ml = rep * 8 + rr;
                const u16x8 vo = *(const u16x8*)(sT + ml * 72 + ch * 8);
                *(u16x8*)(out + (size_t)(m0 + wmh * 128 + h2 * 64 + ml) * N + n0 + wn + ch * 8) = vo;
            }
        }
    }
}

// ---------------------------------------------------------------------------
// kstat_chunk: per-chunk column (max, expsum) of k [B*L, C] bf16.
// grid (C/64, B*8), 256 thr. Chunk = 512 rows. stats[b*C+c][ch] float2.
// ---------------------------------------------------------------------------
__global__ __launch_bounds__(256) void kstat_chunk(const ushort* __restrict__ k,
                                                   float2* __restrict__ stats)
{
    const int cg = blockIdx.x;            // col group (64 cols)
    const int bc = blockIdx.y;            // b*8 + ch
    const int b = bc >> 3, ch = bc & 7;
    const int tid = threadIdx.x;
    const int g = tid & 7;                // 8-col subgroup
    const int kk = tid >> 3;              // 0..31 row worker
    const int w = tid >> 6, lane = tid & 63;
    const ushort* base = k + ((size_t)(b * L_) + ch * 512) * C_ + cg * 64 + g * 8;

    __shared__ float red[4][8][8];
    __shared__ float mcol[64];

    float fm[8];
#pragma unroll
    for (int i = 0; i < 8; ++i) fm[i] = -3.0e38f;
    for (int r = kk; r < 512; r += 32) {
        u16x8 v = *(const u16x8*)(base + (size_t)r * C_);
#pragma unroll
        for (int i = 0; i < 8; ++i) fm[i] = fmaxf(fm[i], bf2f(v[i]));
    }
#pragma unroll
    for (int off = 8; off <= 32; off <<= 1)
#pragma unroll
        for (int i = 0; i < 8; ++i) fm[i] = fmaxf(fm[i], __shfl_xor(fm[i], off));
    if ((lane >> 3) == 0)
#pragma unroll
        for (int i = 0; i < 8; ++i) red[w][g][i] = fm[i];
    __syncthreads();
    if (tid < 64) {
        const int g2 = tid >> 3, j = tid & 7;
        mcol[g2 * 8 + j] = fmaxf(fmaxf(red[0][g2][j], red[1][g2][j]),
                                 fmaxf(red[2][g2][j], red[3][g2][j]));
    }
    __syncthreads();
    float fmc[8];
#pragma unroll
    for (int i = 0; i < 8; ++i) fmc[i] = mcol[g * 8 + i];

    float fs[8] = {};
    for (int r = kk; r < 512; r += 32) {
        u16x8 v = *(const u16x8*)(base + (size_t)r * C_);
#pragma unroll
        for (int i = 0; i < 8; ++i) fs[i] += __expf(bf2f(v[i]) - fmc[i]);
    }
#pragma unroll
    for (int off = 8; off <= 32; off <<= 1)
#pragma unroll
        for (int i = 0; i < 8; ++i) fs[i] += __shfl_xor(fs[i], off);
    __syncthreads();
    if ((lane >> 3) == 0)
#pragma unroll
        for (int i = 0; i < 8; ++i) red[w][g][i] = fs[i];
    __syncthreads();
    if (tid < 64) {
        const int g2 = tid >> 3, j = tid & 7;
        const float s = red[0][g2][j] + red[1][g2][j] + red[2][g2][j] + red[3][g2][j];
        const int c = cg * 64 + g2 * 8 + j;
        stats[((size_t)(b * C_ + c)) * 8 + ch] = make_float2(mcol[g2 * 8 + j], s);
    }
}

// ---------------------------------------------------------------------------
// kstat_merge: global (m, 1/S) per (b,c) from 8 chunk stats.
// ---------------------------------------------------------------------------
__global__ __launch_bounds__(256) void kstat_merge(const float2* __restrict__ stats,
                                                   float2* __restrict__ minv)
{
    const int i = blockIdx.x * 256 + threadIdx.x;
    if (i >= B_ * C_) return;
    float2 st[8];
    float m = -3.0e38f;
#pragma unroll
    for (int ch = 0; ch < 8; ++ch) { st[ch] = stats[(size_t)i * 8 + ch]; m = fmaxf(m, st[ch].x); }
    float s = 0.f;
#pragma unroll
    for (int ch = 0; ch < 8; ++ch) s += st[ch].y * __expf(st[ch].x - m);
    minv[i] = make_float2(m, 1.f / s);
}

// ---------------------------------------------------------------------------
// ctx_mfma: ctxT[bh][dv][dk] += sum_l V[l][dv] * softmaxK[l][dk]  via MFMA.
// K (exp applied, bf16) and V staged TRANSPOSED [c][l] in LDS (stride 72);
// wave w computes dv rows [w*16, w*16+16) with mfma(vf, kf): D-row <-> first
// operand (harness-verified convention). grid (16, B*H), 256 thr.
// Threads 0..127 stage K (exp), 128..255 stage V (transpose passthrough).
// ---------------------------------------------------------------------------
__global__ __launch_bounds__(256) void ctx_mfma(
    const ushort* __restrict__ kk, const ushort* __restrict__ vv,
    const float2* __restrict__ minv, float* __restrict__ ctx)
{
    const int bh = blockIdx.y, b = bh >> 3, h = bh & 7;
    const int l0 = blockIdx.x * 256;
    const int tid = threadIdx.x, w = tid >> 6, lane = tid & 63;
    const int l16 = lane & 15, quad = lane >> 4;

    __shared__ ushort sK[64 * 72];   // [dk][l], stride 72 ushorts
    __shared__ ushort sV[64 * 72];   // [dv][l]

    const int grp = tid >> 7;        // 0 => K (exp), 1 => V
    const int st  = tid & 127;
    const int sc8 = (st & 7) * 8;    // c base 0..56
    const int sl4 = (st >> 3) * 4;   // l base 0..60
    const ushort* gsrc = (grp ? vv : kk)
        + ((size_t)(b * L_ + l0 + sl4)) * C_ + h * 64 + sc8;
    ushort* dst = grp ? sV : sK;

    float2 cst[8];
#pragma unroll
    for (int i = 0; i < 8; ++i)
        cst[i] = minv[(size_t)b * C_ + h * 64 + sc8 + i];

    f32x4_t acc[4];
#pragma unroll
    for (int j = 0; j < 4; ++j) acc[j] = (f32x4_t){0.f, 0.f, 0.f, 0.f};

    for (int tile = 0; tile < 4; ++tile) {
        u16x8 vr[4];
#pragma unroll
        for (int j = 0; j < 4; ++j)
            vr[j] = *(const u16x8*)(gsrc + ((size_t)(tile * 64 + j)) * C_);
        __syncthreads();              // prior tile's frag reads complete
        if (grp == 0) {
#pragma unroll
            for (int c = 0; c < 8; ++c) {
                u16x4 o;
#pragma unroll
                for (int j = 0; j < 4; ++j)
                    o[j] = f2bf(__expf(bf2f(vr[j][c]) - cst[c].x) * cst[c].y);
                *(u16x4*)(dst + (sc8 + c) * 72 + sl4) = o;
            }
        } else {
#pragma unroll
            for (int c = 0; c < 8; ++c) {
                u16x4 o;
#pragma unroll
                for (int j = 0; j < 4; ++j) o[j] = vr[j][c];
                *(u16x4*)(dst + (sc8 + c) * 72 + sl4) = o;
            }
        }
        __syncthreads();
#pragma unroll
        for (int k0 = 0; k0 < 64; k0 += 32) {
            const bf16x8_t vf = *(const bf16x8_t*)(sV + (w * 16 + l16) * 72 + k0 + quad * 8);
#pragma unroll
            for (int j = 0; j < 4; ++j) {
                const bf16x8_t kf = *(const bf16x8_t*)(sK + (j * 16 + l16) * 72 + k0 + quad * 8);
                acc[j] = __builtin_amdgcn_mfma_f32_16x16x32_bf16(vf, kf, acc[j], 0, 0, 0);
            }
        }
    }
    // acc[j][r]: dv = w*16 + quad*4 + r, dk = j*16 + l16
    float* cp = ctx + (size_t)bh * 4096;
#pragma unroll
    for (int j = 0; j < 4; ++j)
#pragma unroll
        for (int r = 0; r < 4; ++r)
            atomicAdd(&cp[(w * 16 + quad * 4 + r) * 64 + (j * 16 + l16)], acc[j][r]);
}

// ---------------------------------------------------------------------------
// att_mfma: att[b,l,h*64+dv] = sum_dk softmax_q[...dk] * ctxT[bh][dv][dk]
// q is RAW logits; per-row softmax over 64 dk fused into the staging loop
// (8 lanes/row shuffle-reduce). grid (L/128, B*H), 256 thr.
// ---------------------------------------------------------------------------
__global__ __launch_bounds__(256) void att_mfma(
    const ushort* __restrict__ q, const float* __restrict__ ctx,
    ushort* __restrict__ att)
{
    const int bh = blockIdx.y, b = bh >> 3, h = bh & 7;
    const int l0 = blockIdx.x * 128;
    const int tid = threadIdx.x, w = tid >> 6, lane = tid & 63;
    const int l16 = lane & 15, quad = lane >> 4;

    __shared__ ushort sQ[128 * 72];   // [l][dk]
    __shared__ ushort sC[64 * 72];    // [dv][dk]

    {
        const int part = tid & 7;
#pragma unroll
        for (int rr = tid >> 3; rr < 128; rr += 32) {
            u16x8 v = *(const u16x8*)(q + ((size_t)(b * L_ + l0 + rr)) * C_ + h * 64 + part * 8);
            float f[8], m = -3.0e38f;
#pragma unroll
            for (int i = 0; i < 8; ++i) { f[i] = bf2f(v[i]); m = fmaxf(m, f[i]); }
            m = fmaxf(m, __shfl_xor(m, 1));
            m = fmaxf(m, __shfl_xor(m, 2));
            m = fmaxf(m, __shfl_xor(m, 4));
            float s = 0.f;
#pragma unroll
            for (int i = 0; i < 8; ++i) { f[i] = __expf(f[i] - m); s += f[i]; }
            s += __shfl_xor(s, 1); s += __shfl_xor(s, 2); s += __shfl_xor(s, 4);
            const float inv = 1.f / s;
            u16x8 o;
#pragma unroll
            for (int i = 0; i < 8; ++i) o[i] = f2bf(f[i] * inv);
            *(u16x8*)(sQ + rr * 72 + part * 8) = o;
        }
        const int dv = tid >> 2, dk0 = (tid & 3) * 16;
        const float* cp = ctx + (size_t)bh * 4096 + dv * 64 + dk0;
#pragma unroll
        for (int i = 0; i < 16; ++i) sC[dv * 72 + dk0 + i] = f2bf(cp[i]);
    }
    __syncthreads();

    f32x4_t acc[2][4];
#pragma unroll
    for (int i = 0; i < 2; ++i)
#pragma unroll
        for (int j = 0; j < 4; ++j) acc[i][j] = (f32x4_t){0.f, 0.f, 0.f, 0.f};

#pragma unroll
    for (int ks = 0; ks < 2; ++ks) {
        const int k0 = ks * 32;
        bf16x8_t aq[2], bc[4];
#pragma unroll
        for (int i = 0; i < 2; ++i)
            aq[i] = *(const bf16x8_t*)(sQ + (w * 32 + i * 16 + l16) * 72 + k0 + quad * 8);
#pragma unroll
        for (int j = 0; j < 4; ++j)
            bc[j] = *(const bf16x8_t*)(sC + (j * 16 + l16) * 72 + k0 + quad * 8);
#pragma unroll
        for (int i = 0; i < 2; ++i)
#pragma unroll
            for (int j = 0; j < 4; ++j)
                acc[i][j] = __builtin_amdgcn_mfma_f32_16x16x32_bf16(aq[i], bc[j], acc[i][j], 0, 0, 0);
    }

#pragma unroll
    for (int j = 0; j < 4; ++j)
#pragma unroll
        for (int i = 0; i < 2; ++i) {
            const int mb = l0 + w * 32 + i * 16 + quad * 4;
#pragma unroll
            for (int r = 0; r < 4; ++r)
                att[((size_t)(b * L_ + mb + r)) * C_ + h * 64 + j * 16 + l16] = f2bf(acc[i][j][r]);
        }
}

// ---------------------------------------------------------------------------
// LayerNorm over 512 contiguous channels; wave per row.
// ---------------------------------------------------------------------------
template<bool OUTF32>
__global__ __launch_bounds__(256) void ln_row(
    const ushort* __restrict__ in, const float* __restrict__ g,
    const float* __restrict__ be, ushort* __restrict__ outb,
    float* __restrict__ outf)
{
    const int tid = threadIdx.x, w = tid >> 6, lane = tid & 63;
    const size_t row = (size_t)blockIdx.x * 4 + w;
    const ushort* p = in + row * C_ + lane * 8;
    u16x8 v = *(const u16x8*)p;
    float f[8], s = 0.f, s2 = 0.f;
#pragma unroll
    for (int i = 0; i < 8; ++i) { f[i] = bf2f(v[i]); s += f[i]; s2 = fmaf(f[i], f[i], s2); }
#pragma unroll
    for (int o = 1; o < 64; o <<= 1) { s += __shfl_xor(s, o); s2 += __shfl_xor(s2, o); }
    const float mean = s * (1.f / C_);
    const float var  = s2 * (1.f / C_) - mean * mean;
    const float inv  = rsqrtf(var + 1e-5f);
    if (OUTF32) {
        float* op = outf + row * C_ + lane * 8;
#pragma unroll
        for (int i = 0; i < 8; ++i)
            op[i] = (f[i] - mean) * inv * g[lane * 8 + i] + be[lane * 8 + i];
    } else {
        u16x8 ov;
#pragma unroll
        for (int i = 0; i < 8; ++i)
            ov[i] = f2bf((f[i] - mean) * inv * g[lane * 8 + i] + be[lane * 8 + i]);
        *(u16x8*)(outb + row * C_ + lane * 8) = ov;
    }
}

// ---------------------------------------------------------------------------
extern "C" void kernel_launch(void* const* d_in, const int* in_sizes, int n_in,
                              void* d_out, int out_size, void* d_ws, size_t ws_size,
                              hipStream_t stream)
{
    const float* z1  = (const float*)d_in[0];
    const float* z2  = (const float*)d_in[1];
    const float* Wq  = (const float*)d_in[2];
    const float* bq  = (const float*)d_in[3];
    const float* Wk  = (const float*)d_in[4];
    const float* bk  = (const float*)d_in[5];
    const float* Wv  = (const float*)d_in[6];
    const float* bv  = (const float*)d_in[7];
    const float* Wr  = (const float*)d_in[8];
    const float* br  = (const float*)d_in[9];
    const float* g1  = (const float*)d_in[10];
    const float* be1 = (const float*)d_in[11];
    const float* W1  = (const float*)d_in[12];
    const float* b1  = (const float*)d_in[13];
    const float* W2  = (const float*)d_in[14];
    const float* b2  = (const float*)d_in[15];
    const float* g2  = (const float*)d_in[16];
    const float* be2 = (const float*)d_in[17];
    float* out = (float*)d_out;

    const size_t SB = (size_t)B_ * L_ * C_;     // 16.78M elems per bf16 buffer
    ushort* ws16 = (ushort*)d_ws;
    ushort* b0v = ws16;            // z1t -> y
    ushort* b1v = ws16 + SB;       // z2t -> att
    ushort* b2v = ws16 + 2 * SB;   // q(raw) -> z -> yf32(lo)
    ushort* b3v = ws16 + 3 * SB;   // k(raw) -> x -> yf32(hi)
    ushort* wb  = ws16 + 4 * SB;   // bf16 weights (4MB)
    ushort* wbq = wb;
    ushort* wbk = wb + 262144;
    ushort* wbv = wb + 524288;
    ushort* wbr = wb + 786432;
    ushort* wb1 = wb + 1048576;
    ushort* wb2 = wb + 1572864;
    float*  ctxf = (float*)(wb + 2097152);       // [B*H,64,64] fp32 (256KB)
    float2* stats = (float2*)(ctxf + 65536);     // [B*C][8] (256KB)
    float2* minv  = stats + (size_t)B_ * C_ * 8; // [B*C] (32KB)
    ushort* vbuf = (ushort*)d_out;               // v lives in d_out
    ushort* hbuf = (ushort*)d_out;               // h: [B*L, 1024] bf16
    float*  yf32 = (float*)b2v;                  // spans b2v+b3v

    const dim3 blk(256);
    const dim3 blk512(512);
    const int M = B_ * L_;   // 32768

    // 0) input transposes + weight casts
    transpose_in<<<dim3(L_/64, C_/64, B_), blk, 0, stream>>>(z1, b0v);
    transpose_in<<<dim3(L_/64, C_/64, B_), blk, 0, stream>>>(z2, b1v);
    cvt_bf16<<<dim3(262144/4/256), blk, 0, stream>>>(Wq, wbq, 262144/4);
    cvt_bf16<<<dim3(262144/4/256), blk, 0, stream>>>(Wk, wbk, 262144/4);
    cvt_bf16<<<dim3(262144/4/256), blk, 0, stream>>>(Wv, wbv, 262144/4);
    cvt_bf16<<<dim3(262144/4/256), blk, 0, stream>>>(Wr, wbr, 262144/4);
    cvt_bf16<<<dim3(524288/4/256), blk, 0, stream>>>(W1, wb1, 524288/4);
    cvt_bf16<<<dim3(524288/4/256), blk, 0, stream>>>(W2, wb2, 524288/4);

    // 1) projections (MFMA); q and k stay RAW logits
    conv_mfma<0,false><<<dim3(M/256, C_/256), blk512, 0, stream>>>(b0v, wbq, bq, nullptr, b2v, M, C_, C_);
    conv_mfma<0,false><<<dim3(M/256, C_/256), blk512, 0, stream>>>(b1v, wbk, bk, nullptr, b3v, M, C_, C_);
    conv_mfma<0,false><<<dim3(M/256, C_/256), blk512, 0, stream>>>(b1v, wbv, bv, nullptr, vbuf, M, C_, C_);

    // 2) k-softmax stats (parallel, chunked)
    kstat_chunk<<<dim3(C_/64, B_ * 8), blk, 0, stream>>>(b3v, stats);
    kstat_merge<<<dim3((B_ * C_ + 255) / 256), blk, 0, stream>>>(stats, minv);

    // 3) ctxT = V^T softmax(K)  (softmax fused, MFMA, fp32 atomics, 16 l-splits)
    zero_kernel<<<dim3(65536/256), blk, 0, stream>>>(ctxf, 65536);
    ctx_mfma<<<dim3(16, B_ * H_), blk, 0, stream>>>(b3v, vbuf, minv, ctxf);

    // 4) att = softmax(q) . ctxT^T per head (q-softmax fused); att -> b1v
    att_mfma<<<dim3(L_/128, B_ * H_), blk, 0, stream>>>(b2v, ctxf, b1v);

    // 5) z = Wr@att + br + z1t  -> b2v (q dead)
    conv_mfma<0,true><<<dim3(M/256, C_/256), blk512, 0, stream>>>(b1v, wbr, br, b0v, b2v, M, C_, C_);

    // 6) x = LN1(z) -> b3v (k dead)
    ln_row<false><<<dim3(M/4), blk, 0, stream>>>(b2v, g1, be1, b3v, nullptr);

    // 7) h = ELU(W1@x) -> d_out (v dead)
    conv_mfma<1,false><<<dim3(M/256, C2_/256), blk512, 0, stream>>>(b3v, wb1, b1, nullptr, hbuf, M, C2_, C_);

    // 8) y = W2@h -> b0v (z1t dead)
    conv_mfma<0,false><<<dim3(M/256, C_/256), blk512, 0, stream>>>(hbuf, wb2, b2, nullptr, b0v, M, C_, C2_);

    // 9) LN2 -> fp32 [B*L,C] into b2v+b3v region (z,x dead)
    ln_row<true><<<dim3(M/4), blk, 0, stream>>>(b0v, g2, be2, nullptr, yf32);

    // 10) transpose to [B,C,L] fp32 -> d_out (h dead)
    transpose_out<<<dim3(L_/64, C_/64, B_), blk, 0, stream>>>(yf32, out);
}